// Round 7
// baseline (503.852 us; speedup 1.0000x reference)
//
#include <hip/hip_runtime.h>

typedef __bf16 bf16x8 __attribute__((ext_vector_type(8)));
typedef float  f32x4  __attribute__((ext_vector_type(4)));
typedef float  f32x16 __attribute__((ext_vector_type(16)));

__device__ __forceinline__ unsigned short f2b(float f) {
    union { float f; unsigned int v; } c; c.f = f;
    unsigned int u = c.v;
    unsigned int r = u + 0x7FFFu + ((u >> 16) & 1u);   // RNE
    return (unsigned short)(r >> 16);
}
__device__ __forceinline__ f32x4 mfma16(bf16x8 a, bf16x8 b, f32x4 c) {
    return __builtin_amdgcn_mfma_f32_16x16x32_bf16(a, b, c, 0, 0, 0);
}
__device__ __forceinline__ f32x16 mfma32(bf16x8 a, bf16x8 b, f32x16 c) {
    return __builtin_amdgcn_mfma_f32_32x32x16_bf16(a, b, c, 0, 0, 0);
}
// pack two f32 -> 2xbf16 in one u32 (lo = a, hi = b), RNE
__device__ __forceinline__ unsigned cvtpk(float a, float b) {
    unsigned r;
    asm("v_cvt_pk_bf16_f32 %0, %1, %2" : "=v"(r) : "v"(a), "v"(b));
    return r;
}

// ---------------- constants ----------------
#define BB 8
#define SS 2048
#define DD 256
#define HH 4
#define FF 512
#define MM (BB * SS)   // 16384
// log2(e) folded into Q scale so softmax uses exp2 directly
#define QSCALE (0.0625f * 1.44269504088896340736f)

// ---------------- transpose f32 -> bf16 with scale ----------------
__global__ __launch_bounds__(256) void transpose_f32_kernel(
    const float* __restrict__ in, unsigned short* __restrict__ out,
    int inS, int outS, long long inZa, long long inZb, int zmod, long long outZ,
    float scale)
{
    __shared__ unsigned short T[64][72];
    const int z = blockIdx.z;
    in  += (long long)(z / zmod) * inZa + (long long)(z % zmod) * inZb;
    out += (long long)z * outZ;
    const int r0 = blockIdx.x * 64, c0 = blockIdx.y * 64;
    const int tid = threadIdx.x;
    const int row = tid >> 3;           // 0..31
    const int col = (tid & 7) * 8;      // 0..56
#pragma unroll
    for (int c = 0; c < 2; ++c) {
        int rr = c * 32 + row;
        const float4 a = *reinterpret_cast<const float4*>(&in[(long long)(r0 + rr) * inS + c0 + col]);
        const float4 b = *reinterpret_cast<const float4*>(&in[(long long)(r0 + rr) * inS + c0 + col + 4]);
        alignas(16) unsigned short t[8] = {
            f2b(a.x * scale), f2b(a.y * scale), f2b(a.z * scale), f2b(a.w * scale),
            f2b(b.x * scale), f2b(b.y * scale), f2b(b.z * scale), f2b(b.w * scale) };
        *reinterpret_cast<uint4*>(&T[rr][col]) = *reinterpret_cast<const uint4*>(t);
    }
    __syncthreads();
#pragma unroll
    for (int c = 0; c < 2; ++c) {
        int orow = c * 32 + row;
        alignas(16) unsigned short tmp[8];
#pragma unroll
        for (int j = 0; j < 8; ++j) tmp[j] = T[col + j][orow];
        *reinterpret_cast<uint4*>(&out[(long long)(c0 + orow) * outS + r0 + col]) =
            *reinterpret_cast<const uint4*>(tmp);
    }
}

// ---------------- bias concat: qkb[2048] = {bq*QSCALE, bk}, vb[1024] = bv ----------------
__global__ __launch_bounds__(256) void bias_concat_kernel(
    const float* __restrict__ bq, const float* __restrict__ bk,
    const float* __restrict__ bv, float* __restrict__ qkb, float* __restrict__ vb)
{
    const int i = blockIdx.x * 256 + threadIdx.x;
    if (i < 1024)       qkb[i] = bq[i] * QSCALE;
    else if (i < 2048)  qkb[i] = bk[i - 1024];
    else                vb[i - 2048] = bv[i - 2048];
}

// ---------------- LayerNorm: one wave per 256-elem row, f32 in -> bf16 out ----------------
__global__ __launch_bounds__(256) void ln_kernel(
    const float* __restrict__ in, const float* __restrict__ g,
    const float* __restrict__ bta, unsigned short* __restrict__ out)
{
    const int tid  = threadIdx.x;
    const int wave = tid >> 6, lane = tid & 63;
    const int row  = blockIdx.x * 4 + wave;
    const float4 v = reinterpret_cast<const float4*>(in)[(long long)row * 64 + lane];
    float x[4] = { v.x, v.y, v.z, v.w };
    float s = x[0] + x[1] + x[2] + x[3];
    float q = x[0]*x[0] + x[1]*x[1] + x[2]*x[2] + x[3]*x[3];
#pragma unroll
    for (int off = 1; off < 64; off <<= 1) {
        s += __shfl_xor(s, off);
        q += __shfl_xor(q, off);
    }
    const float mean = s * (1.0f / 256.0f);
    const float var  = q * (1.0f / 256.0f) - mean * mean;
    const float rs   = rsqrtf(var + 1e-5f);
    const float4 gv = reinterpret_cast<const float4*>(g)[lane];
    const float4 bv = reinterpret_cast<const float4*>(bta)[lane];
    unsigned short y[4];
    y[0] = f2b((x[0] - mean) * rs * gv.x + bv.x);
    y[1] = f2b((x[1] - mean) * rs * gv.y + bv.y);
    y[2] = f2b((x[2] - mean) * rs * gv.z + bv.z);
    y[3] = f2b((x[3] - mean) * rs * gv.w + bv.w);
    uint2 o;
    o.x = (unsigned int)y[0] | ((unsigned int)y[1] << 16);
    o.y = (unsigned int)y[2] | ((unsigned int)y[3] << 16);
    reinterpret_cast<uint2*>(out)[(long long)row * 64 + lane] = o;
}

// ---------------- GEMM: C[MxN] = A[MxK] @ B  (B given as BT[N x K], bf16) ----------------
// Double-buffered LDS, reg-prefetch of tile k+1 before computing tile k, ds_write after
// compute, ONE barrier per K-step (same pipeline proven in attn). Round-1 epilogue.
template <bool RELU, int RES, bool OUTBF, int NS, bool VT>
__global__ __launch_bounds__(256) void gemm_kernel(
    const unsigned short* __restrict__ A, const unsigned short* __restrict__ BT,
    const float* __restrict__ bias, const float* __restrict__ res,
    void* __restrict__ out, int M, int N, int K)
{
    __shared__ unsigned short As[2][128 * 40];
    __shared__ unsigned short Bs[2][(NS == 4 ? 128 : 64) * 40];
    const int tid  = threadIdx.x;
    const int wave = tid >> 6, lane = tid & 63;
    const int quad = lane >> 4, l16 = lane & 15;
    const int wm = wave >> 1, wn = wave & 1;
    const int WN = NS * 16;                        // wave n-width
    const int m0 = blockIdx.x * 128, n0 = blockIdx.y * (2 * WN);

    f32x4 acc[4][NS];
#pragma unroll
    for (int i = 0; i < 4; ++i)
#pragma unroll
        for (int j = 0; j < NS; ++j) acc[i][j] = (f32x4){0.f, 0.f, 0.f, 0.f};

    const int srow = tid >> 2;          // 0..63
    const int scol = (tid & 3) * 8;     // 0,8,16,24

    uint4 areg[2], breg[2];
    // prologue: stage K-tile 0 into buffer 0
#pragma unroll
    for (int c = 0; c < 2; ++c)
        areg[c] = *reinterpret_cast<const uint4*>(&A[(long long)(m0 + c * 64 + srow) * K + scol]);
    breg[0] = *reinterpret_cast<const uint4*>(&BT[(long long)(n0 + srow) * K + scol]);
    if (NS == 4)
        breg[1] = *reinterpret_cast<const uint4*>(&BT[(long long)(n0 + 64 + srow) * K + scol]);
#pragma unroll
    for (int c = 0; c < 2; ++c)
        *reinterpret_cast<uint4*>(&As[0][(c * 64 + srow) * 40 + scol]) = areg[c];
    *reinterpret_cast<uint4*>(&Bs[0][srow * 40 + scol]) = breg[0];
    if (NS == 4)
        *reinterpret_cast<uint4*>(&Bs[0][(64 + srow) * 40 + scol]) = breg[1];
    __syncthreads();

    const int nk = K >> 5;
    for (int it = 0; it < nk; ++it) {
        const int cur = it & 1;
        // issue next-tile global loads first; latency hides under this iteration's MFMA
        if (it + 1 < nk) {
            const int k0 = (it + 1) * 32;
#pragma unroll
            for (int c = 0; c < 2; ++c)
                areg[c] = *reinterpret_cast<const uint4*>(&A[(long long)(m0 + c * 64 + srow) * K + k0 + scol]);
            breg[0] = *reinterpret_cast<const uint4*>(&BT[(long long)(n0 + srow) * K + k0 + scol]);
            if (NS == 4)
                breg[1] = *reinterpret_cast<const uint4*>(&BT[(long long)(n0 + 64 + srow) * K + k0 + scol]);
        }

        bf16x8 af[4], bf[NS];
#pragma unroll
        for (int ms = 0; ms < 4; ++ms)
            af[ms] = *reinterpret_cast<const bf16x8*>(&As[cur][(wm * 64 + ms * 16 + l16) * 40 + quad * 8]);
#pragma unroll
        for (int ns = 0; ns < NS; ++ns)
            bf[ns] = *reinterpret_cast<const bf16x8*>(&Bs[cur][(wn * WN + ns * 16 + l16) * 40 + quad * 8]);
#pragma unroll
        for (int ms = 0; ms < 4; ++ms)
#pragma unroll
            for (int ns = 0; ns < NS; ++ns)
                acc[ms][ns] = mfma16(af[ms], bf[ns], acc[ms][ns]);

        // write next tile into the other buffer, single barrier per K-step
        if (it + 1 < nk) {
            const int nxt = cur ^ 1;
#pragma unroll
            for (int c = 0; c < 2; ++c)
                *reinterpret_cast<uint4*>(&As[nxt][(c * 64 + srow) * 40 + scol]) = areg[c];
            *reinterpret_cast<uint4*>(&Bs[nxt][srow * 40 + scol]) = breg[0];
            if (NS == 4)
                *reinterpret_cast<uint4*>(&Bs[nxt][(64 + srow) * 40 + scol]) = breg[1];
            __syncthreads();
        }
    }

    // epilogue (round-1 layout: col = l16, rows = quad*4+r)
#pragma unroll
    for (int ms = 0; ms < 4; ++ms) {
#pragma unroll
        for (int ns = 0; ns < NS; ++ns) {
            const int cg = n0 + wn * WN + ns * 16 + l16;
            const float bvc = VT ? 0.f : bias[cg];
#pragma unroll
            for (int r = 0; r < 4; ++r) {
                const int rg = m0 + wm * 64 + ms * 16 + quad * 4 + r;
                float v = acc[ms][ns][r] + (VT ? bias[rg] : bvc);
                if (RELU)   v = fmaxf(v, 0.0f);
                if (RES == 1)
                    v += res[(long long)rg * N + cg];
                if (VT) {
                    // rg = h*256+e (M=1024), cg = b*2048+t (N=16384) -> vt[(b*4+h)][e][t]
                    const long long oaddr =
                        (long long)((cg >> 11) * 4 + (rg >> 8)) * 524288 +
                        (long long)(rg & 255) * 2048 + (cg & 2047);
                    reinterpret_cast<unsigned short*>(out)[oaddr] = f2b(v);
                } else if (OUTBF) {
                    reinterpret_cast<unsigned short*>(out)[(long long)rg * N + cg] = f2b(v);
                } else {
                    reinterpret_cast<float*>(out)[(long long)rg * N + cg] = v;
                }
            }
        }
    }
}

// ---------------- Flash attention (round-1 proven structure, exp2 softmax) ----------------
// K and V double-buffered in LDS via reg staging; in-register P (swapped QK^T + cvt_pk +
// permlane32_swap); single sc chain; 1 barrier/iter. LDS 74752 B -> 2 blocks/CU.
__global__ __launch_bounds__(256, 2) void attn_kernel(
    const unsigned short* __restrict__ QK, const unsigned short* __restrict__ Vt,
    unsigned short* __restrict__ Cat)
{
    __shared__ __align__(16) unsigned short Ks[2][32 * 264];   // [t][d], stride 264
    __shared__ __align__(16) unsigned short Vs[2][256 * 40];   // [e][t], stride 40
    const int tid  = threadIdx.x;
    const int wave = tid >> 6, lane = tid & 63;
    const int l32 = lane & 31, half = lane >> 5;
    const int by = blockIdx.x;              // b*4 + h
    const int h = by & 3, b = by >> 2;
    const int q0 = blockIdx.y * 128;
    const unsigned short* Qb = QK + (long long)b * SS * 2048 + h * 256;
    const unsigned short* Kb = Qb + 1024;
    const unsigned short* vbase = Vt + (long long)by * DD * SS;

    // Q fragments, 32 rows/wave: lane holds Q[q0+w*32+l32][kb*16 + half*8 + j]
    bf16x8 qf[16];
    {
        const unsigned short* qrow = Qb + (long long)(q0 + wave * 32 + l32) * 2048 + half * 8;
#pragma unroll
        for (int kb = 0; kb < 16; ++kb)
            qf[kb] = *reinterpret_cast<const bf16x8*>(qrow + kb * 16);
    }

    f32x16 o[8];
#pragma unroll
    for (int i = 0; i < 8; ++i)
#pragma unroll
        for (int r = 0; r < 16; ++r) o[i][r] = 0.f;
    float lsum = 0.f;   // per-lane partial row-sum for q = l32 (this half's t-subset)

    const int krow = tid >> 3;          // 0..31
    const int kcol = (tid & 7) * 8;     // 0..56 (shorts)
    const int ve   = tid >> 2;          // 0..63 (base V row)
    const int vtf  = (tid & 3) * 8;     // 0..24 (t offset, shorts)

    uint4 kreg[4], vreg[4];
    // prologue: stage tile 0 into buffer 0
#pragma unroll
    for (int c = 0; c < 4; ++c)
        kreg[c] = *reinterpret_cast<const uint4*>(&Kb[(long long)krow * 2048 + kcol + c * 64]);
#pragma unroll
    for (int c = 0; c < 4; ++c)
        vreg[c] = *reinterpret_cast<const uint4*>(&vbase[(long long)(ve + c * 64) * SS + vtf]);
#pragma unroll
    for (int c = 0; c < 4; ++c)
        *reinterpret_cast<uint4*>(&Ks[0][krow * 264 + kcol + c * 64]) = kreg[c];
#pragma unroll
    for (int c = 0; c < 4; ++c)
        *reinterpret_cast<uint4*>(&Vs[0][(ve + c * 64) * 40 + vtf]) = vreg[c];
    __syncthreads();

    for (int t = 0; t < 64; ++t) {
        const int cur = t & 1;
        // issue next-tile global loads early (latency hides under compute)
        if (t < 63) {
            const int t1 = (t + 1) * 32;
#pragma unroll
            for (int c = 0; c < 4; ++c)
                kreg[c] = *reinterpret_cast<const uint4*>(&Kb[(long long)(t1 + krow) * 2048 + kcol + c * 64]);
#pragma unroll
            for (int c = 0; c < 4; ++c)
                vreg[c] = *reinterpret_cast<const uint4*>(&vbase[(long long)(ve + c * 64) * SS + t1 + vtf]);
        }

        // swapped QK^T: sc = K_tile . Q^T -> lane holds S[q=l32][t-subset]
        f32x16 sc;
#pragma unroll
        for (int r = 0; r < 16; ++r) sc[r] = 0.f;
        __builtin_amdgcn_s_setprio(1);
#pragma unroll
        for (int kb = 0; kb < 16; ++kb) {
            bf16x8 kf = *reinterpret_cast<const bf16x8*>(&Ks[cur][l32 * 264 + kb * 16 + half * 8]);
            sc = mfma32(kf, qf[kb], sc);
        }
        __builtin_amdgcn_s_setprio(0);

        // softmax numerator: p = exp2(s) (log2e folded into Q scale)
        float p[16];
#pragma unroll
        for (int r = 0; r < 16; ++r) {
            p[r] = exp2f(sc[r]);
            lsum += p[r];
        }

        // pack P -> PV A-fragments fully in-register (cvt_pk + permlane32_swap)
        unsigned pk[8];
#pragma unroll
        for (int i = 0; i < 8; ++i) pk[i] = cvtpk(p[2 * i], p[2 * i + 1]);
        union { bf16x8 v; unsigned u[4]; } A0, A1;   // A0: t=0..15, A1: t=16..31
        { auto rr = __builtin_amdgcn_permlane32_swap(pk[0], pk[2], false, false); A0.u[0] = rr[0]; A0.u[2] = rr[1]; }
        { auto rr = __builtin_amdgcn_permlane32_swap(pk[1], pk[3], false, false); A0.u[1] = rr[0]; A0.u[3] = rr[1]; }
        { auto rr = __builtin_amdgcn_permlane32_swap(pk[4], pk[6], false, false); A1.u[0] = rr[0]; A1.u[2] = rr[1]; }
        { auto rr = __builtin_amdgcn_permlane32_swap(pk[5], pk[7], false, false); A1.u[1] = rr[0]; A1.u[3] = rr[1]; }

        // PV: B = V^T tile from Vs; 8 e-tiles x 2 k-steps
        __builtin_amdgcn_s_setprio(1);
#pragma unroll
        for (int et = 0; et < 8; ++et) {
            bf16x8 vf0 = *reinterpret_cast<const bf16x8*>(&Vs[cur][(et * 32 + l32) * 40 + half * 8]);
            bf16x8 vf1 = *reinterpret_cast<const bf16x8*>(&Vs[cur][(et * 32 + l32) * 40 + 16 + half * 8]);
            o[et] = mfma32(A0.v, vf0, o[et]);
            o[et] = mfma32(A1.v, vf1, o[et]);
        }
        __builtin_amdgcn_s_setprio(0);

        // write next tile into the other buffer, then single barrier
        if (t < 63) {
            const int nxt = cur ^ 1;
#pragma unroll
            for (int c = 0; c < 4; ++c)
                *reinterpret_cast<uint4*>(&Ks[nxt][krow * 264 + kcol + c * 64]) = kreg[c];
#pragma unroll
            for (int c = 0; c < 4; ++c)
                *reinterpret_cast<uint4*>(&Vs[nxt][(ve + c * 64) * 40 + vtf]) = vreg[c];
            __syncthreads();
        }
    }

    // epilogue: full row-sum for q=l32 lives split across the two halves
    lsum += __shfl_xor(lsum, 32);
    const float inv = 1.0f / lsum;
    float invr[16];
#pragma unroll
    for (int r = 0; r < 16; ++r)
        invr[r] = __shfl(inv, (r & 3) + 8 * (r >> 2) + 4 * half);

    const int rowb = b * SS + q0 + wave * 32;
#pragma unroll
    for (int et = 0; et < 8; ++et) {
        const int cg = h * 256 + et * 32 + l32;
#pragma unroll
        for (int r = 0; r < 16; ++r) {
            const int row = (r & 3) + 8 * (r >> 2) + 4 * half;
            Cat[(long long)(rowb + row) * (HH * DD) + cg] = f2b(o[et][r] * invr[r]);
        }
    }
}

// ---------------- launch ----------------
extern "C" void kernel_launch(void* const* d_in, const int* in_sizes, int n_in,
                              void* d_out, int out_size, void* d_ws, size_t ws_size,
                              hipStream_t stream)
{
    const float* x   = (const float*)d_in[0];
    const float* Wq  = (const float*)d_in[1];
    const float* bq  = (const float*)d_in[2];
    const float* Wk  = (const float*)d_in[3];
    const float* bk  = (const float*)d_in[4];
    const float* Wv  = (const float*)d_in[5];
    const float* bv  = (const float*)d_in[6];
    const float* Wo  = (const float*)d_in[7];
    const float* bo  = (const float*)d_in[8];
    const float* g1  = (const float*)d_in[9];
    const float* be1 = (const float*)d_in[10];
    const float* g2  = (const float*)d_in[11];
    const float* be2 = (const float*)d_in[12];
    const float* W1  = (const float*)d_in[13];
    const float* bf1 = (const float*)d_in[14];
    const float* W2  = (const float*)d_in[15];
    const float* bf2 = (const float*)d_in[16];
    float* out = (float*)d_out;

    // ---- workspace layout ----
    char* ws = (char*)d_ws;
    unsigned short* xn1  = (unsigned short*)(ws + 0);           // [16384][256] bf16
    unsigned short* qk   = (unsigned short*)(ws + 8388608);     // [16384][2048] bf16 (Q|K by head)
    unsigned short* cat  = (unsigned short*)(ws + 75497472);    // [16384][1024] bf16
    unsigned short* vt   = (unsigned short*)(ws + 109051904);   // [32][256][2048] bf16
    unsigned short* wqkT = (unsigned short*)(ws + 142606336);   // [2048][256] bf16
    unsigned short* wvT  = (unsigned short*)(ws + 143654912);   // [1024][256] bf16
    unsigned short* woT  = (unsigned short*)(ws + 144179200);   // [256][1024] bf16
    unsigned short* w1T  = (unsigned short*)(ws + 144703488);   // [512][256] bf16
    unsigned short* w2T  = (unsigned short*)(ws + 144965632);   // [256][512] bf16
    float*          qkb  = (float*)(ws + 145227776);            // [2048] f32
    float*          vb   = (float*)(ws + 145235968);            // [1024] f32
    // aliases over dead regions:
    float*          xmid = (float*)(ws + 8388608);              // (qk dead after attn)
    unsigned short* xn2  = (unsigned short*)(ws + 25165824);
    unsigned short* mid  = (unsigned short*)(ws + 33554432);

    // weight transposes (Q scale: 1/16 * log2(e) folded for exp2 softmax)
    transpose_f32_kernel<<<dim3(4, 4, 4),  256, 0, stream>>>(Wq, wqkT,          256,  256, 0, 65536, 4, 65536, QSCALE);
    transpose_f32_kernel<<<dim3(4, 4, 4),  256, 0, stream>>>(Wk, wqkT + 262144, 256,  256, 0, 65536, 4, 65536, 1.0f);
    transpose_f32_kernel<<<dim3(4, 4, 4),  256, 0, stream>>>(Wv, wvT,           256,  256, 0, 65536, 4, 65536, 1.0f);
    transpose_f32_kernel<<<dim3(16, 4, 1), 256, 0, stream>>>(Wo, woT,           256, 1024, 0, 0, 4, 0, 1.0f);
    transpose_f32_kernel<<<dim3(4, 8, 1),  256, 0, stream>>>(W1, w1T,           512,  256, 0, 0, 4, 0, 1.0f);
    transpose_f32_kernel<<<dim3(8, 4, 1),  256, 0, stream>>>(W2, w2T,           256,  512, 0, 0, 4, 0, 1.0f);
    bias_concat_kernel<<<dim3(12), 256, 0, stream>>>(bq, bk, bv, qkb, vb);

    // LN1
    ln_kernel<<<dim3(4096), 256, 0, stream>>>(x, g1, be1, xn1);

    // fused Q|K projection (2048 blocks)
    gemm_kernel<false, 0, true, 4, false><<<dim3(128, 16), 256, 0, stream>>>(
        xn1, wqkT, qkb, nullptr, qk, MM, 2048, 256);
    // V^T projection straight into vt layout (1024 blocks)
    gemm_kernel<false, 0, true, 4, true><<<dim3(8, 128), 256, 0, stream>>>(
        wvT, xn1, vb, nullptr, vt, 1024, MM, 256);

    // flash attention (32x32 MFMA, 128 q-rows/block, 512 blocks = 2/CU)
    attn_kernel<<<dim3(32, 16), 256, 0, stream>>>(qk, vt, cat);

    // Wo projection + residual(x) -> xmid (f32); 128x64 tiles -> 512 blocks
    gemm_kernel<false, 1, false, 2, false><<<dim3(128, 4), 256, 0, stream>>>(
        cat, woT, bo, x, xmid, MM, 256, 1024);

    // LN2
    ln_kernel<<<dim3(4096), 256, 0, stream>>>(xmid, g2, be2, xn2);

    // FFN1 + ReLU; 128x64 tiles -> 1024 blocks
    gemm_kernel<true, 0, true, 2, false><<<dim3(128, 8), 256, 0, stream>>>(
        xn2, w1T, bf1, nullptr, mid, MM, 512, 256);

    // FFN2 + residual(xmid) -> d_out (f32); 128x64 tiles -> 512 blocks
    gemm_kernel<false, 1, false, 2, false><<<dim3(128, 4), 256, 0, stream>>>(
        mid, w2T, bf2, xmid, out, MM, 256, 512);

    (void)in_sizes; (void)n_in; (void)out_size; (void)ws_size;
}

// Round 8
// 496.945 us; speedup vs baseline: 1.0139x; 1.0139x over previous
//
#include <hip/hip_runtime.h>

typedef __bf16 bf16x8 __attribute__((ext_vector_type(8)));
typedef float  f32x4  __attribute__((ext_vector_type(4)));
typedef float  f32x16 __attribute__((ext_vector_type(16)));

__device__ __forceinline__ unsigned short f2b(float f) {
    union { float f; unsigned int v; } c; c.f = f;
    unsigned int u = c.v;
    unsigned int r = u + 0x7FFFu + ((u >> 16) & 1u);   // RNE
    return (unsigned short)(r >> 16);
}
__device__ __forceinline__ f32x4 mfma16(bf16x8 a, bf16x8 b, f32x4 c) {
    return __builtin_amdgcn_mfma_f32_16x16x32_bf16(a, b, c, 0, 0, 0);
}
__device__ __forceinline__ f32x16 mfma32(bf16x8 a, bf16x8 b, f32x16 c) {
    return __builtin_amdgcn_mfma_f32_32x32x16_bf16(a, b, c, 0, 0, 0);
}
// pack two f32 -> 2xbf16 in one u32 (lo = a, hi = b), RNE
__device__ __forceinline__ unsigned cvtpk(float a, float b) {
    unsigned r;
    asm("v_cvt_pk_bf16_f32 %0, %1, %2" : "=v"(r) : "v"(a), "v"(b));
    return r;
}

// ---------------- constants ----------------
#define BB 8
#define SS 2048
#define DD 256
#define HH 4
#define FF 512
#define MM (BB * SS)   // 16384

// ---------------- transpose f32 -> bf16 with scale ----------------
__global__ __launch_bounds__(256) void transpose_f32_kernel(
    const float* __restrict__ in, unsigned short* __restrict__ out,
    int inS, int outS, long long inZa, long long inZb, int zmod, long long outZ,
    float scale)
{
    __shared__ unsigned short T[64][72];
    const int z = blockIdx.z;
    in  += (long long)(z / zmod) * inZa + (long long)(z % zmod) * inZb;
    out += (long long)z * outZ;
    const int r0 = blockIdx.x * 64, c0 = blockIdx.y * 64;
    const int tid = threadIdx.x;
    const int row = tid >> 3;           // 0..31
    const int col = (tid & 7) * 8;      // 0..56
#pragma unroll
    for (int c = 0; c < 2; ++c) {
        int rr = c * 32 + row;
        const float4 a = *reinterpret_cast<const float4*>(&in[(long long)(r0 + rr) * inS + c0 + col]);
        const float4 b = *reinterpret_cast<const float4*>(&in[(long long)(r0 + rr) * inS + c0 + col + 4]);
        alignas(16) unsigned short t[8] = {
            f2b(a.x * scale), f2b(a.y * scale), f2b(a.z * scale), f2b(a.w * scale),
            f2b(b.x * scale), f2b(b.y * scale), f2b(b.z * scale), f2b(b.w * scale) };
        *reinterpret_cast<uint4*>(&T[rr][col]) = *reinterpret_cast<const uint4*>(t);
    }
    __syncthreads();
#pragma unroll
    for (int c = 0; c < 2; ++c) {
        int orow = c * 32 + row;
        alignas(16) unsigned short tmp[8];
#pragma unroll
        for (int j = 0; j < 8; ++j) tmp[j] = T[col + j][orow];
        *reinterpret_cast<uint4*>(&out[(long long)(c0 + orow) * outS + r0 + col]) =
            *reinterpret_cast<const uint4*>(tmp);
    }
}

// ---------------- bias concat: qkb[2048] = {bq*1/16, bk}, vb[1024] = bv ----------------
__global__ __launch_bounds__(256) void bias_concat_kernel(
    const float* __restrict__ bq, const float* __restrict__ bk,
    const float* __restrict__ bv, float* __restrict__ qkb, float* __restrict__ vb)
{
    const int i = blockIdx.x * 256 + threadIdx.x;
    if (i < 1024)       qkb[i] = bq[i] * 0.0625f;
    else if (i < 2048)  qkb[i] = bk[i - 1024];
    else                vb[i - 2048] = bv[i - 2048];
}

// ---------------- LayerNorm: one wave per 256-elem row, f32 in -> bf16 out ----------------
__global__ __launch_bounds__(256) void ln_kernel(
    const float* __restrict__ in, const float* __restrict__ g,
    const float* __restrict__ bta, unsigned short* __restrict__ out)
{
    const int tid  = threadIdx.x;
    const int wave = tid >> 6, lane = tid & 63;
    const int row  = blockIdx.x * 4 + wave;
    const float4 v = reinterpret_cast<const float4*>(in)[(long long)row * 64 + lane];
    float x[4] = { v.x, v.y, v.z, v.w };
    float s = x[0] + x[1] + x[2] + x[3];
    float q = x[0]*x[0] + x[1]*x[1] + x[2]*x[2] + x[3]*x[3];
#pragma unroll
    for (int off = 1; off < 64; off <<= 1) {
        s += __shfl_xor(s, off);
        q += __shfl_xor(q, off);
    }
    const float mean = s * (1.0f / 256.0f);
    const float var  = q * (1.0f / 256.0f) - mean * mean;
    const float rs   = rsqrtf(var + 1e-5f);
    const float4 gv = reinterpret_cast<const float4*>(g)[lane];
    const float4 bv = reinterpret_cast<const float4*>(bta)[lane];
    unsigned short y[4];
    y[0] = f2b((x[0] - mean) * rs * gv.x + bv.x);
    y[1] = f2b((x[1] - mean) * rs * gv.y + bv.y);
    y[2] = f2b((x[2] - mean) * rs * gv.z + bv.z);
    y[3] = f2b((x[3] - mean) * rs * gv.w + bv.w);
    uint2 o;
    o.x = (unsigned int)y[0] | ((unsigned int)y[1] << 16);
    o.y = (unsigned int)y[2] | ((unsigned int)y[3] << 16);
    reinterpret_cast<uint2*>(out)[(long long)row * 64 + lane] = o;
}

// ---------------- GEMM: C[MxN] = A[MxK] @ B  (B given as BT[N x K], bf16) ----------------
// Round-1 single-buffer structure (occupancy-preserving), with ONE change: the next
// K-tile's global loads are issued AFTER barrier-2, so their latency hides under the
// fragment reads + MFMA of the current tile instead of sitting between the barriers.
template <bool RELU, int RES, bool OUTBF, int NS, bool VT>
__global__ __launch_bounds__(256) void gemm_kernel(
    const unsigned short* __restrict__ A, const unsigned short* __restrict__ BT,
    const float* __restrict__ bias, const float* __restrict__ res,
    void* __restrict__ out, int M, int N, int K)
{
    __shared__ unsigned short As[128 * 40];
    __shared__ unsigned short Bs[(NS == 4 ? 128 : 64) * 40];
    const int tid  = threadIdx.x;
    const int wave = tid >> 6, lane = tid & 63;
    const int quad = lane >> 4, l16 = lane & 15;
    const int wm = wave >> 1, wn = wave & 1;
    const int WN = NS * 16;                        // wave n-width
    const int m0 = blockIdx.x * 128, n0 = blockIdx.y * (2 * WN);

    f32x4 acc[4][NS];
#pragma unroll
    for (int i = 0; i < 4; ++i)
#pragma unroll
        for (int j = 0; j < NS; ++j) acc[i][j] = (f32x4){0.f, 0.f, 0.f, 0.f};

    const int srow = tid >> 2;          // 0..63
    const int scol = (tid & 3) * 8;     // 0,8,16,24

    uint4 areg[2], breg[2];
    // preload K-tile 0 into registers
#pragma unroll
    for (int c = 0; c < 2; ++c)
        areg[c] = *reinterpret_cast<const uint4*>(&A[(long long)(m0 + c * 64 + srow) * K + scol]);
    breg[0] = *reinterpret_cast<const uint4*>(&BT[(long long)(n0 + srow) * K + scol]);
    if (NS == 4)
        breg[1] = *reinterpret_cast<const uint4*>(&BT[(long long)(n0 + 64 + srow) * K + scol]);

    const int nk = K >> 5;
    for (int it = 0; it < nk; ++it) {
        __syncthreads();    // previous iteration's fragment readers done
#pragma unroll
        for (int c = 0; c < 2; ++c)
            *reinterpret_cast<uint4*>(&As[(c * 64 + srow) * 40 + scol]) = areg[c];
        *reinterpret_cast<uint4*>(&Bs[srow * 40 + scol]) = breg[0];
        if (NS == 4)
            *reinterpret_cast<uint4*>(&Bs[(64 + srow) * 40 + scol]) = breg[1];
        __syncthreads();    // writes visible

        // issue next-tile loads now: a full compute phase of latency slack
        if (it + 1 < nk) {
            const int k0 = (it + 1) * 32;
#pragma unroll
            for (int c = 0; c < 2; ++c)
                areg[c] = *reinterpret_cast<const uint4*>(&A[(long long)(m0 + c * 64 + srow) * K + k0 + scol]);
            breg[0] = *reinterpret_cast<const uint4*>(&BT[(long long)(n0 + srow) * K + k0 + scol]);
            if (NS == 4)
                breg[1] = *reinterpret_cast<const uint4*>(&BT[(long long)(n0 + 64 + srow) * K + k0 + scol]);
        }

        bf16x8 af[4], bf[NS];
#pragma unroll
        for (int ms = 0; ms < 4; ++ms)
            af[ms] = *reinterpret_cast<const bf16x8*>(&As[(wm * 64 + ms * 16 + l16) * 40 + quad * 8]);
#pragma unroll
        for (int ns = 0; ns < NS; ++ns)
            bf[ns] = *reinterpret_cast<const bf16x8*>(&Bs[(wn * WN + ns * 16 + l16) * 40 + quad * 8]);
#pragma unroll
        for (int ms = 0; ms < 4; ++ms)
#pragma unroll
            for (int ns = 0; ns < NS; ++ns)
                acc[ms][ns] = mfma16(af[ms], bf[ns], acc[ms][ns]);
    }

    // epilogue
#pragma unroll
    for (int ms = 0; ms < 4; ++ms) {
#pragma unroll
        for (int ns = 0; ns < NS; ++ns) {
            const int cg = n0 + wn * WN + ns * 16 + l16;
            const float bvc = VT ? 0.f : bias[cg];
#pragma unroll
            for (int r = 0; r < 4; ++r) {
                const int rg = m0 + wm * 64 + ms * 16 + quad * 4 + r;
                float v = acc[ms][ns][r] + (VT ? bias[rg] : bvc);
                if (RELU)   v = fmaxf(v, 0.0f);
                if (RES == 1)
                    v += res[(long long)rg * N + cg];
                if (VT) {
                    // rg = h*256+e (M=1024), cg = b*2048+t (N=16384) -> vt[(b*4+h)][e][t]
                    const long long oaddr =
                        (long long)((cg >> 11) * 4 + (rg >> 8)) * 524288 +
                        (long long)(rg & 255) * 2048 + (cg & 2047);
                    reinterpret_cast<unsigned short*>(out)[oaddr] = f2b(v);
                } else if (OUTBF) {
                    reinterpret_cast<unsigned short*>(out)[(long long)rg * N + cg] = f2b(v);
                } else {
                    reinterpret_cast<float*>(out)[(long long)rg * N + cg] = v;
                }
            }
        }
    }
}

// ---------------- Flash attention (round-1 exact: 143.2 us measured) ----------------
// K and V double-buffered in LDS via reg staging; in-register P (swapped QK^T + cvt_pk +
// permlane32_swap); split sc chains; __expf softmax; 1 barrier/iter.
// LDS: 2*(32*264 + 256*40)*2B = 74752 B -> 2 blocks/CU.
__global__ __launch_bounds__(256, 2) void attn_kernel(
    const unsigned short* __restrict__ QK, const unsigned short* __restrict__ Vt,
    unsigned short* __restrict__ Cat)
{
    __shared__ __align__(16) unsigned short Ks[2][32 * 264];   // [t][d], stride 264
    __shared__ __align__(16) unsigned short Vs[2][256 * 40];   // [e][t], stride 40
    const int tid  = threadIdx.x;
    const int wave = tid >> 6, lane = tid & 63;
    const int l32 = lane & 31, half = lane >> 5;
    const int by = blockIdx.x;              // b*4 + h
    const int h = by & 3, b = by >> 2;
    const int q0 = blockIdx.y * 128;
    const unsigned short* Qb = QK + (long long)b * SS * 2048 + h * 256;
    const unsigned short* Kb = Qb + 1024;
    const unsigned short* vbase = Vt + (long long)by * DD * SS;

    // Q fragments, 32 rows/wave: lane holds Q[q0+w*32+l32][kb*16 + half*8 + j]
    bf16x8 qf[16];
    {
        const unsigned short* qrow = Qb + (long long)(q0 + wave * 32 + l32) * 2048 + half * 8;
#pragma unroll
        for (int kb = 0; kb < 16; ++kb)
            qf[kb] = *reinterpret_cast<const bf16x8*>(qrow + kb * 16);
    }

    f32x16 o[8];
#pragma unroll
    for (int i = 0; i < 8; ++i)
#pragma unroll
        for (int r = 0; r < 16; ++r) o[i][r] = 0.f;
    float lsum = 0.f;   // per-lane partial row-sum for q = l32 (this half's t-subset)

    const int krow = tid >> 3;          // 0..31
    const int kcol = (tid & 7) * 8;     // 0..56 (shorts)
    const int ve   = tid >> 2;          // 0..63 (base V row)
    const int vtf  = (tid & 3) * 8;     // 0..24 (t offset, shorts)

    uint4 kreg[4], vreg[4];
    // prologue: stage tile 0 into buffer 0
#pragma unroll
    for (int c = 0; c < 4; ++c)
        kreg[c] = *reinterpret_cast<const uint4*>(&Kb[(long long)krow * 2048 + kcol + c * 64]);
#pragma unroll
    for (int c = 0; c < 4; ++c)
        vreg[c] = *reinterpret_cast<const uint4*>(&vbase[(long long)(ve + c * 64) * SS + vtf]);
#pragma unroll
    for (int c = 0; c < 4; ++c)
        *reinterpret_cast<uint4*>(&Ks[0][krow * 264 + kcol + c * 64]) = kreg[c];
#pragma unroll
    for (int c = 0; c < 4; ++c)
        *reinterpret_cast<uint4*>(&Vs[0][(ve + c * 64) * 40 + vtf]) = vreg[c];
    __syncthreads();

    for (int t = 0; t < 64; ++t) {
        const int cur = t & 1;
        // issue next-tile global loads early (latency hides under compute)
        if (t < 63) {
            const int t1 = (t + 1) * 32;
#pragma unroll
            for (int c = 0; c < 4; ++c)
                kreg[c] = *reinterpret_cast<const uint4*>(&Kb[(long long)(t1 + krow) * 2048 + kcol + c * 64]);
#pragma unroll
            for (int c = 0; c < 4; ++c)
                vreg[c] = *reinterpret_cast<const uint4*>(&vbase[(long long)(ve + c * 64) * SS + t1 + vtf]);
        }

        // swapped QK^T: sc = K_tile . Q^T -> lane holds S[q=l32][t-subset], split acc chain
        f32x16 sc0, sc1;
#pragma unroll
        for (int r = 0; r < 16; ++r) { sc0[r] = 0.f; sc1[r] = 0.f; }
        __builtin_amdgcn_s_setprio(1);
#pragma unroll
        for (int kb = 0; kb < 8; ++kb) {
            bf16x8 kf0 = *reinterpret_cast<const bf16x8*>(&Ks[cur][l32 * 264 + (2 * kb) * 16 + half * 8]);
            bf16x8 kf1 = *reinterpret_cast<const bf16x8*>(&Ks[cur][l32 * 264 + (2 * kb + 1) * 16 + half * 8]);
            sc0 = mfma32(kf0, qf[2 * kb], sc0);
            sc1 = mfma32(kf1, qf[2 * kb + 1], sc1);
        }
        __builtin_amdgcn_s_setprio(0);

        // softmax numerator: p = exp(s); accumulate row-sums per lane
        float p[16];
#pragma unroll
        for (int r = 0; r < 16; ++r) {
            p[r] = __expf(sc0[r] + sc1[r]);
            lsum += p[r];
        }

        // pack P -> PV A-fragments fully in-register (cvt_pk + permlane32_swap)
        unsigned pk[8];
#pragma unroll
        for (int i = 0; i < 8; ++i) pk[i] = cvtpk(p[2 * i], p[2 * i + 1]);
        union { bf16x8 v; unsigned u[4]; } A0, A1;   // A0: t=0..15, A1: t=16..31
        { auto rr = __builtin_amdgcn_permlane32_swap(pk[0], pk[2], false, false); A0.u[0] = rr[0]; A0.u[2] = rr[1]; }
        { auto rr = __builtin_amdgcn_permlane32_swap(pk[1], pk[3], false, false); A0.u[1] = rr[0]; A0.u[3] = rr[1]; }
        { auto rr = __builtin_amdgcn_permlane32_swap(pk[4], pk[6], false, false); A1.u[0] = rr[0]; A1.u[2] = rr[1]; }
        { auto rr = __builtin_amdgcn_permlane32_swap(pk[5], pk[7], false, false); A1.u[1] = rr[0]; A1.u[3] = rr[1]; }

        // PV: B = V^T tile from Vs; 8 e-tiles x 2 k-steps
        __builtin_amdgcn_s_setprio(1);
#pragma unroll
        for (int et = 0; et < 8; ++et) {
            bf16x8 vf0 = *reinterpret_cast<const bf16x8*>(&Vs[cur][(et * 32 + l32) * 40 + half * 8]);
            bf16x8 vf1 = *reinterpret_cast<const bf16x8*>(&Vs[cur][(et * 32 + l32) * 40 + 16 + half * 8]);
            o[et] = mfma32(A0.v, vf0, o[et]);
            o[et] = mfma32(A1.v, vf1, o[et]);
        }
        __builtin_amdgcn_s_setprio(0);

        // write next tile into the other buffer, then single barrier
        if (t < 63) {
            const int nxt = cur ^ 1;
#pragma unroll
            for (int c = 0; c < 4; ++c)
                *reinterpret_cast<uint4*>(&Ks[nxt][krow * 264 + kcol + c * 64]) = kreg[c];
#pragma unroll
            for (int c = 0; c < 4; ++c)
                *reinterpret_cast<uint4*>(&Vs[nxt][(ve + c * 64) * 40 + vtf]) = vreg[c];
            __syncthreads();
        }
    }

    // epilogue: full row-sum for q=l32 lives split across the two halves
    lsum += __shfl_xor(lsum, 32);
    const float inv = 1.0f / lsum;
    float invr[16];
#pragma unroll
    for (int r = 0; r < 16; ++r)
        invr[r] = __shfl(inv, (r & 3) + 8 * (r >> 2) + 4 * half);

    const int rowb = b * SS + q0 + wave * 32;
#pragma unroll
    for (int et = 0; et < 8; ++et) {
        const int cg = h * 256 + et * 32 + l32;
#pragma unroll
        for (int r = 0; r < 16; ++r) {
            const int row = (r & 3) + 8 * (r >> 2) + 4 * half;
            Cat[(long long)(rowb + row) * (HH * DD) + cg] = f2b(o[et][r] * invr[r]);
        }
    }
}

// ---------------- launch ----------------
extern "C" void kernel_launch(void* const* d_in, const int* in_sizes, int n_in,
                              void* d_out, int out_size, void* d_ws, size_t ws_size,
                              hipStream_t stream)
{
    const float* x   = (const float*)d_in[0];
    const float* Wq  = (const float*)d_in[1];
    const float* bq  = (const float*)d_in[2];
    const float* Wk  = (const float*)d_in[3];
    const float* bk  = (const float*)d_in[4];
    const float* Wv  = (const float*)d_in[5];
    const float* bv  = (const float*)d_in[6];
    const float* Wo  = (const float*)d_in[7];
    const float* bo  = (const float*)d_in[8];
    const float* g1  = (const float*)d_in[9];
    const float* be1 = (const float*)d_in[10];
    const float* g2  = (const float*)d_in[11];
    const float* be2 = (const float*)d_in[12];
    const float* W1  = (const float*)d_in[13];
    const float* bf1 = (const float*)d_in[14];
    const float* W2  = (const float*)d_in[15];
    const float* bf2 = (const float*)d_in[16];
    float* out = (float*)d_out;

    // ---- workspace layout ----
    char* ws = (char*)d_ws;
    unsigned short* xn1  = (unsigned short*)(ws + 0);           // [16384][256] bf16
    unsigned short* qk   = (unsigned short*)(ws + 8388608);     // [16384][2048] bf16 (Q|K by head)
    unsigned short* cat  = (unsigned short*)(ws + 75497472);    // [16384][1024] bf16
    unsigned short* vt   = (unsigned short*)(ws + 109051904);   // [32][256][2048] bf16
    unsigned short* wqkT = (unsigned short*)(ws + 142606336);   // [2048][256] bf16
    unsigned short* wvT  = (unsigned short*)(ws + 143654912);   // [1024][256] bf16
    unsigned short* woT  = (unsigned short*)(ws + 144179200);   // [256][1024] bf16
    unsigned short* w1T  = (unsigned short*)(ws + 144703488);   // [512][256] bf16
    unsigned short* w2T  = (unsigned short*)(ws + 144965632);   // [256][512] bf16
    float*          qkb  = (float*)(ws + 145227776);            // [2048] f32
    float*          vb   = (float*)(ws + 145235968);            // [1024] f32
    // aliases over dead regions:
    float*          xmid = (float*)(ws + 8388608);              // (qk dead after attn)
    unsigned short* xn2  = (unsigned short*)(ws + 25165824);
    unsigned short* mid  = (unsigned short*)(ws + 33554432);

    // weight transposes (scale 1/16 folded into Wq — exact, power of 2)
    transpose_f32_kernel<<<dim3(4, 4, 4),  256, 0, stream>>>(Wq, wqkT,          256,  256, 0, 65536, 4, 65536, 0.0625f);
    transpose_f32_kernel<<<dim3(4, 4, 4),  256, 0, stream>>>(Wk, wqkT + 262144, 256,  256, 0, 65536, 4, 65536, 1.0f);
    transpose_f32_kernel<<<dim3(4, 4, 4),  256, 0, stream>>>(Wv, wvT,           256,  256, 0, 65536, 4, 65536, 1.0f);
    transpose_f32_kernel<<<dim3(16, 4, 1), 256, 0, stream>>>(Wo, woT,           256, 1024, 0, 0, 4, 0, 1.0f);
    transpose_f32_kernel<<<dim3(4, 8, 1),  256, 0, stream>>>(W1, w1T,           512,  256, 0, 0, 4, 0, 1.0f);
    transpose_f32_kernel<<<dim3(8, 4, 1),  256, 0, stream>>>(W2, w2T,           256,  512, 0, 0, 4, 0, 1.0f);
    bias_concat_kernel<<<dim3(12), 256, 0, stream>>>(bq, bk, bv, qkb, vb);

    // LN1
    ln_kernel<<<dim3(4096), 256, 0, stream>>>(x, g1, be1, xn1);

    // fused Q|K projection (2048 blocks)
    gemm_kernel<false, 0, true, 4, false><<<dim3(128, 16), 256, 0, stream>>>(
        xn1, wqkT, qkb, nullptr, qk, MM, 2048, 256);
    // V^T projection straight into vt layout (1024 blocks)
    gemm_kernel<false, 0, true, 4, true><<<dim3(8, 128), 256, 0, stream>>>(
        wvT, xn1, vb, nullptr, vt, 1024, MM, 256);

    // flash attention (32x32 MFMA, 128 q-rows/block, 512 blocks = 2/CU)
    attn_kernel<<<dim3(32, 16), 256, 0, stream>>>(qk, vt, cat);

    // Wo projection + residual(x) -> xmid (f32); 128x64 tiles -> 512 blocks
    gemm_kernel<false, 1, false, 2, false><<<dim3(128, 4), 256, 0, stream>>>(
        cat, woT, bo, x, xmid, MM, 256, 1024);

    // LN2
    ln_kernel<<<dim3(4096), 256, 0, stream>>>(xmid, g2, be2, xn2);

    // FFN1 + ReLU; 128x64 tiles -> 1024 blocks
    gemm_kernel<true, 0, true, 2, false><<<dim3(128, 8), 256, 0, stream>>>(
        xn2, w1T, bf1, nullptr, mid, MM, 512, 256);

    // FFN2 + residual(xmid) -> d_out (f32); 128x64 tiles -> 512 blocks
    gemm_kernel<false, 1, false, 2, false><<<dim3(128, 4), 256, 0, stream>>>(
        mid, w2T, bf2, xmid, out, MM, 256, 512);

    (void)in_sizes; (void)n_in; (void)out_size; (void)ws_size;
}

// Round 9
// 346.352 us; speedup vs baseline: 1.4547x; 1.4348x over previous
//
#include <hip/hip_runtime.h>

typedef __bf16 bf16x8 __attribute__((ext_vector_type(8)));
typedef float  f32x4  __attribute__((ext_vector_type(4)));
typedef float  f32x16 __attribute__((ext_vector_type(16)));

__device__ __forceinline__ unsigned short f2b(float f) {
    union { float f; unsigned int v; } c; c.f = f;
    unsigned int u = c.v;
    unsigned int r = u + 0x7FFFu + ((u >> 16) & 1u);   // RNE
    return (unsigned short)(r >> 16);
}
__device__ __forceinline__ f32x4 mfma16(bf16x8 a, bf16x8 b, f32x4 c) {
    return __builtin_amdgcn_mfma_f32_16x16x32_bf16(a, b, c, 0, 0, 0);
}
__device__ __forceinline__ f32x16 mfma32(bf16x8 a, bf16x8 b, f32x16 c) {
    return __builtin_amdgcn_mfma_f32_32x32x16_bf16(a, b, c, 0, 0, 0);
}
// pack two f32 -> 2xbf16 in one u32 (lo = a, hi = b), RNE
__device__ __forceinline__ unsigned cvtpk(float a, float b) {
    unsigned r;
    asm("v_cvt_pk_bf16_f32 %0, %1, %2" : "=v"(r) : "v"(a), "v"(b));
    return r;
}

// ---------------- constants ----------------
#define BB 8
#define SS 2048
#define DD 256
#define HH 4
#define FF 512
#define MM (BB * SS)   // 16384

// ---------------- fused prologue: 6 weight transposes + bias concat + LN1 ----------------
// blocks 0..319: transposes; 320..331: bias concat; 332..4427: LN1 (4 rows/block).
__device__ __forceinline__ void transpose_body(
    const float* __restrict__ in, unsigned short* __restrict__ out,
    int inS, int outS, int r0, int c0, float scale,
    unsigned short (*T)[72])
{
    const int tid = threadIdx.x;
    const int row = tid >> 3;           // 0..31
    const int col = (tid & 7) * 8;      // 0..56
#pragma unroll
    for (int c = 0; c < 2; ++c) {
        int rr = c * 32 + row;
        const float4 a = *reinterpret_cast<const float4*>(&in[(long long)(r0 + rr) * inS + c0 + col]);
        const float4 b = *reinterpret_cast<const float4*>(&in[(long long)(r0 + rr) * inS + c0 + col + 4]);
        alignas(16) unsigned short t[8] = {
            f2b(a.x * scale), f2b(a.y * scale), f2b(a.z * scale), f2b(a.w * scale),
            f2b(b.x * scale), f2b(b.y * scale), f2b(b.z * scale), f2b(b.w * scale) };
        *reinterpret_cast<uint4*>(&T[rr][col]) = *reinterpret_cast<const uint4*>(t);
    }
    __syncthreads();
#pragma unroll
    for (int c = 0; c < 2; ++c) {
        int orow = c * 32 + row;
        alignas(16) unsigned short tmp[8];
#pragma unroll
        for (int j = 0; j < 8; ++j) tmp[j] = T[col + j][orow];
        *reinterpret_cast<uint4*>(&out[(long long)(c0 + orow) * outS + r0 + col]) =
            *reinterpret_cast<const uint4*>(tmp);
    }
}

__global__ __launch_bounds__(256) void prologue_kernel(
    const float* __restrict__ Wq, const float* __restrict__ Wk,
    const float* __restrict__ Wv, const float* __restrict__ Wo,
    const float* __restrict__ W1, const float* __restrict__ W2,
    const float* __restrict__ bq, const float* __restrict__ bk,
    const float* __restrict__ bv,
    const float* __restrict__ x,  const float* __restrict__ g1,
    const float* __restrict__ be1,
    unsigned short* __restrict__ wqkT, unsigned short* __restrict__ wvT,
    unsigned short* __restrict__ woT,  unsigned short* __restrict__ w1T,
    unsigned short* __restrict__ w2T,
    float* __restrict__ qkb, float* __restrict__ vb,
    unsigned short* __restrict__ xn1)
{
    __shared__ unsigned short T[64][72];
    const int blk = blockIdx.x;
    if (blk < 320) {
        const float* in; unsigned short* out; int inS, outS, r0, c0; float scale;
        if (blk < 192) {                       // Wq | Wk | Wv : per-head 256x256
            const int w = blk >> 6;            // 0,1,2
            const int b = blk & 63;
            const int z = b >> 4;              // head
            in  = (w == 0 ? Wq : w == 1 ? Wk : Wv) + z * 65536;
            out = (w == 0 ? wqkT : w == 1 ? wqkT + 262144 : wvT) + z * 65536;
            inS = 256; outS = 256; scale = (w == 0) ? 0.0625f : 1.0f;
            r0 = (b & 3) * 64; c0 = ((b >> 2) & 3) * 64;
        } else if (blk < 256) {                // Wo: 1024x256 -> 256x1024
            const int b = blk - 192;
            in = Wo; out = woT; inS = 256; outS = 1024; scale = 1.0f;
            r0 = (b & 15) * 64; c0 = (b >> 4) * 64;
        } else if (blk < 288) {                // W1: 256x512 -> 512x256
            const int b = blk - 256;
            in = W1; out = w1T; inS = 512; outS = 256; scale = 1.0f;
            r0 = (b & 3) * 64; c0 = (b >> 2) * 64;
        } else {                               // W2: 512x256 -> 256x512
            const int b = blk - 288;
            in = W2; out = w2T; inS = 256; outS = 512; scale = 1.0f;
            r0 = (b & 7) * 64; c0 = (b >> 3) * 64;
        }
        transpose_body(in, out, inS, outS, r0, c0, scale, T);
    } else if (blk < 332) {                    // bias concat
        const int i = (blk - 320) * 256 + threadIdx.x;
        if (i < 1024)       qkb[i] = bq[i] * 0.0625f;
        else if (i < 2048)  qkb[i] = bk[i - 1024];
        else                vb[i - 2048] = bv[i - 2048];
    } else {                                   // LN1, 4 rows/block
        const int tid  = threadIdx.x;
        const int wave = tid >> 6, lane = tid & 63;
        const int row  = (blk - 332) * 4 + wave;
        const float4 v = reinterpret_cast<const float4*>(x)[(long long)row * 64 + lane];
        float xr[4] = { v.x, v.y, v.z, v.w };
        float s = xr[0] + xr[1] + xr[2] + xr[3];
        float q = xr[0]*xr[0] + xr[1]*xr[1] + xr[2]*xr[2] + xr[3]*xr[3];
#pragma unroll
        for (int off = 1; off < 64; off <<= 1) {
            s += __shfl_xor(s, off);
            q += __shfl_xor(q, off);
        }
        const float mean = s * (1.0f / 256.0f);
        const float var  = q * (1.0f / 256.0f) - mean * mean;
        const float rs   = rsqrtf(var + 1e-5f);
        const float4 gv = reinterpret_cast<const float4*>(g1)[lane];
        const float4 bv4 = reinterpret_cast<const float4*>(be1)[lane];
        unsigned short y[4];
        y[0] = f2b((xr[0] - mean) * rs * gv.x + bv4.x);
        y[1] = f2b((xr[1] - mean) * rs * gv.y + bv4.y);
        y[2] = f2b((xr[2] - mean) * rs * gv.z + bv4.z);
        y[3] = f2b((xr[3] - mean) * rs * gv.w + bv4.w);
        uint2 o;
        o.x = (unsigned int)y[0] | ((unsigned int)y[1] << 16);
        o.y = (unsigned int)y[2] | ((unsigned int)y[3] << 16);
        reinterpret_cast<uint2*>(xn1)[(long long)row * 64 + lane] = o;
    }
}

// ---------------- LayerNorm: one wave per 256-elem row, f32 in -> bf16 out ----------------
__global__ __launch_bounds__(256) void ln_kernel(
    const float* __restrict__ in, const float* __restrict__ g,
    const float* __restrict__ bta, unsigned short* __restrict__ out)
{
    const int tid  = threadIdx.x;
    const int wave = tid >> 6, lane = tid & 63;
    const int row  = blockIdx.x * 4 + wave;
    const float4 v = reinterpret_cast<const float4*>(in)[(long long)row * 64 + lane];
    float x[4] = { v.x, v.y, v.z, v.w };
    float s = x[0] + x[1] + x[2] + x[3];
    float q = x[0]*x[0] + x[1]*x[1] + x[2]*x[2] + x[3]*x[3];
#pragma unroll
    for (int off = 1; off < 64; off <<= 1) {
        s += __shfl_xor(s, off);
        q += __shfl_xor(q, off);
    }
    const float mean = s * (1.0f / 256.0f);
    const float var  = q * (1.0f / 256.0f) - mean * mean;
    const float rs   = rsqrtf(var + 1e-5f);
    const float4 gv = reinterpret_cast<const float4*>(g)[lane];
    const float4 bv = reinterpret_cast<const float4*>(bta)[lane];
    unsigned short y[4];
    y[0] = f2b((x[0] - mean) * rs * gv.x + bv.x);
    y[1] = f2b((x[1] - mean) * rs * gv.y + bv.y);
    y[2] = f2b((x[2] - mean) * rs * gv.z + bv.z);
    y[3] = f2b((x[3] - mean) * rs * gv.w + bv.w);
    uint2 o;
    o.x = (unsigned int)y[0] | ((unsigned int)y[1] << 16);
    o.y = (unsigned int)y[2] | ((unsigned int)y[3] << 16);
    reinterpret_cast<uint2*>(out)[(long long)row * 64 + lane] = o;
}

// ---------------- GEMM: C[MxN] = A[MxK] @ B  (B given as BT[N x K], bf16) ----------------
// Round-1 exact: single-buffer LDS, fused global-load -> LDS-write staging, 2 barriers.
// (Register-staged prefetch regressed twice (r7/r8, ~+135us) -- occupancy/TLP loss.)
template <bool RELU, int RES, bool OUTBF, int NS, bool VT>
__global__ __launch_bounds__(256) void gemm_kernel(
    const unsigned short* __restrict__ A, const unsigned short* __restrict__ BT,
    const float* __restrict__ bias, const float* __restrict__ res,
    void* __restrict__ out, int M, int N, int K)
{
    __shared__ unsigned short As[128 * 40];
    __shared__ unsigned short Bs[(NS == 4 ? 128 : 64) * 40];
    const int tid  = threadIdx.x;
    const int wave = tid >> 6, lane = tid & 63;
    const int quad = lane >> 4, l16 = lane & 15;
    const int wm = wave >> 1, wn = wave & 1;
    const int WN = NS * 16;                        // wave n-width
    const int m0 = blockIdx.x * 128, n0 = blockIdx.y * (2 * WN);

    f32x4 acc[4][NS];
#pragma unroll
    for (int i = 0; i < 4; ++i)
#pragma unroll
        for (int j = 0; j < NS; ++j) acc[i][j] = (f32x4){0.f, 0.f, 0.f, 0.f};

    const int srow = tid >> 2;          // 0..63
    const int scol = (tid & 3) * 8;     // 0,8,16,24

    for (int k0 = 0; k0 < K; k0 += 32) {
        __syncthreads();
#pragma unroll
        for (int c = 0; c < 2; ++c) {
            const int r = c * 64 + srow;
            *reinterpret_cast<uint4*>(&As[r * 40 + scol]) =
                *reinterpret_cast<const uint4*>(&A[(long long)(m0 + r) * K + k0 + scol]);
        }
        {
            *reinterpret_cast<uint4*>(&Bs[srow * 40 + scol]) =
                *reinterpret_cast<const uint4*>(&BT[(long long)(n0 + srow) * K + k0 + scol]);
            if (NS == 4) {
                const int r = 64 + srow;
                *reinterpret_cast<uint4*>(&Bs[r * 40 + scol]) =
                    *reinterpret_cast<const uint4*>(&BT[(long long)(n0 + r) * K + k0 + scol]);
            }
        }
        __syncthreads();
        bf16x8 af[4], bf[NS];
#pragma unroll
        for (int ms = 0; ms < 4; ++ms)
            af[ms] = *reinterpret_cast<const bf16x8*>(&As[(wm * 64 + ms * 16 + l16) * 40 + quad * 8]);
#pragma unroll
        for (int ns = 0; ns < NS; ++ns)
            bf[ns] = *reinterpret_cast<const bf16x8*>(&Bs[(wn * WN + ns * 16 + l16) * 40 + quad * 8]);
#pragma unroll
        for (int ms = 0; ms < 4; ++ms)
#pragma unroll
            for (int ns = 0; ns < NS; ++ns)
                acc[ms][ns] = mfma16(af[ms], bf[ns], acc[ms][ns]);
    }

    // epilogue
#pragma unroll
    for (int ms = 0; ms < 4; ++ms) {
#pragma unroll
        for (int ns = 0; ns < NS; ++ns) {
            const int cg = n0 + wn * WN + ns * 16 + l16;
            const float bvc = VT ? 0.f : bias[cg];
#pragma unroll
            for (int r = 0; r < 4; ++r) {
                const int rg = m0 + wm * 64 + ms * 16 + quad * 4 + r;
                float v = acc[ms][ns][r] + (VT ? bias[rg] : bvc);
                if (RELU)   v = fmaxf(v, 0.0f);
                if (RES == 1)
                    v += res[(long long)rg * N + cg];
                if (VT) {
                    // rg = h*256+e (M=1024), cg = b*2048+t (N=16384) -> vt[(b*4+h)][e][t]
                    const long long oaddr =
                        (long long)((cg >> 11) * 4 + (rg >> 8)) * 524288 +
                        (long long)(rg & 255) * 2048 + (cg & 2047);
                    reinterpret_cast<unsigned short*>(out)[oaddr] = f2b(v);
                } else if (OUTBF) {
                    reinterpret_cast<unsigned short*>(out)[(long long)rg * N + cg] = f2b(v);
                } else {
                    reinterpret_cast<float*>(out)[(long long)rg * N + cg] = v;
                }
            }
        }
    }
}

// ---------------- Flash attention (round-1 exact: 139.6-143.2 us measured) ----------------
// K and V double-buffered in LDS via reg staging; in-register P (swapped QK^T + cvt_pk +
// permlane32_swap); split sc chains; __expf softmax; 1 barrier/iter.
// LDS: 2*(32*264 + 256*40)*2B = 74752 B -> 2 blocks/CU.
__global__ __launch_bounds__(256, 2) void attn_kernel(
    const unsigned short* __restrict__ QK, const unsigned short* __restrict__ Vt,
    unsigned short* __restrict__ Cat)
{
    __shared__ __align__(16) unsigned short Ks[2][32 * 264];   // [t][d], stride 264
    __shared__ __align__(16) unsigned short Vs[2][256 * 40];   // [e][t], stride 40
    const int tid  = threadIdx.x;
    const int wave = tid >> 6, lane = tid & 63;
    const int l32 = lane & 31, half = lane >> 5;
    const int by = blockIdx.x;              // b*4 + h
    const int h = by & 3, b = by >> 2;
    const int q0 = blockIdx.y * 128;
    const unsigned short* Qb = QK + (long long)b * SS * 2048 + h * 256;
    const unsigned short* Kb = Qb + 1024;
    const unsigned short* vbase = Vt + (long long)by * DD * SS;

    // Q fragments, 32 rows/wave: lane holds Q[q0+w*32+l32][kb*16 + half*8 + j]
    bf16x8 qf[16];
    {
        const unsigned short* qrow = Qb + (long long)(q0 + wave * 32 + l32) * 2048 + half * 8;
#pragma unroll
        for (int kb = 0; kb < 16; ++kb)
            qf[kb] = *reinterpret_cast<const bf16x8*>(qrow + kb * 16);
    }

    f32x16 o[8];
#pragma unroll
    for (int i = 0; i < 8; ++i)
#pragma unroll
        for (int r = 0; r < 16; ++r) o[i][r] = 0.f;
    float lsum = 0.f;   // per-lane partial row-sum for q = l32 (this half's t-subset)

    const int krow = tid >> 3;          // 0..31
    const int kcol = (tid & 7) * 8;     // 0..56 (shorts)
    const int ve   = tid >> 2;          // 0..63 (base V row)
    const int vtf  = (tid & 3) * 8;     // 0..24 (t offset, shorts)

    uint4 kreg[4], vreg[4];
    // prologue: stage tile 0 into buffer 0
#pragma unroll
    for (int c = 0; c < 4; ++c)
        kreg[c] = *reinterpret_cast<const uint4*>(&Kb[(long long)krow * 2048 + kcol + c * 64]);
#pragma unroll
    for (int c = 0; c < 4; ++c)
        vreg[c] = *reinterpret_cast<const uint4*>(&vbase[(long long)(ve + c * 64) * SS + vtf]);
#pragma unroll
    for (int c = 0; c < 4; ++c)
        *reinterpret_cast<uint4*>(&Ks[0][krow * 264 + kcol + c * 64]) = kreg[c];
#pragma unroll
    for (int c = 0; c < 4; ++c)
        *reinterpret_cast<uint4*>(&Vs[0][(ve + c * 64) * 40 + vtf]) = vreg[c];
    __syncthreads();

    for (int t = 0; t < 64; ++t) {
        const int cur = t & 1;
        // issue next-tile global loads early (latency hides under compute)
        if (t < 63) {
            const int t1 = (t + 1) * 32;
#pragma unroll
            for (int c = 0; c < 4; ++c)
                kreg[c] = *reinterpret_cast<const uint4*>(&Kb[(long long)(t1 + krow) * 2048 + kcol + c * 64]);
#pragma unroll
            for (int c = 0; c < 4; ++c)
                vreg[c] = *reinterpret_cast<const uint4*>(&vbase[(long long)(ve + c * 64) * SS + t1 + vtf]);
        }

        // swapped QK^T: sc = K_tile . Q^T -> lane holds S[q=l32][t-subset], split acc chain
        f32x16 sc0, sc1;
#pragma unroll
        for (int r = 0; r < 16; ++r) { sc0[r] = 0.f; sc1[r] = 0.f; }
        __builtin_amdgcn_s_setprio(1);
#pragma unroll
        for (int kb = 0; kb < 8; ++kb) {
            bf16x8 kf0 = *reinterpret_cast<const bf16x8*>(&Ks[cur][l32 * 264 + (2 * kb) * 16 + half * 8]);
            bf16x8 kf1 = *reinterpret_cast<const bf16x8*>(&Ks[cur][l32 * 264 + (2 * kb + 1) * 16 + half * 8]);
            sc0 = mfma32(kf0, qf[2 * kb], sc0);
            sc1 = mfma32(kf1, qf[2 * kb + 1], sc1);
        }
        __builtin_amdgcn_s_setprio(0);

        // softmax numerator: p = exp(s); accumulate row-sums per lane
        float p[16];
#pragma unroll
        for (int r = 0; r < 16; ++r) {
            p[r] = __expf(sc0[r] + sc1[r]);
            lsum += p[r];
        }

        // pack P -> PV A-fragments fully in-register (cvt_pk + permlane32_swap)
        unsigned pk[8];
#pragma unroll
        for (int i = 0; i < 8; ++i) pk[i] = cvtpk(p[2 * i], p[2 * i + 1]);
        union { bf16x8 v; unsigned u[4]; } A0, A1;   // A0: t=0..15, A1: t=16..31
        { auto rr = __builtin_amdgcn_permlane32_swap(pk[0], pk[2], false, false); A0.u[0] = rr[0]; A0.u[2] = rr[1]; }
        { auto rr = __builtin_amdgcn_permlane32_swap(pk[1], pk[3], false, false); A0.u[1] = rr[0]; A0.u[3] = rr[1]; }
        { auto rr = __builtin_amdgcn_permlane32_swap(pk[4], pk[6], false, false); A1.u[0] = rr[0]; A1.u[2] = rr[1]; }
        { auto rr = __builtin_amdgcn_permlane32_swap(pk[5], pk[7], false, false); A1.u[1] = rr[0]; A1.u[3] = rr[1]; }

        // PV: B = V^T tile from Vs; 8 e-tiles x 2 k-steps
        __builtin_amdgcn_s_setprio(1);
#pragma unroll
        for (int et = 0; et < 8; ++et) {
            bf16x8 vf0 = *reinterpret_cast<const bf16x8*>(&Vs[cur][(et * 32 + l32) * 40 + half * 8]);
            bf16x8 vf1 = *reinterpret_cast<const bf16x8*>(&Vs[cur][(et * 32 + l32) * 40 + 16 + half * 8]);
            o[et] = mfma32(A0.v, vf0, o[et]);
            o[et] = mfma32(A1.v, vf1, o[et]);
        }
        __builtin_amdgcn_s_setprio(0);

        // write next tile into the other buffer, then single barrier
        if (t < 63) {
            const int nxt = cur ^ 1;
#pragma unroll
            for (int c = 0; c < 4; ++c)
                *reinterpret_cast<uint4*>(&Ks[nxt][krow * 264 + kcol + c * 64]) = kreg[c];
#pragma unroll
            for (int c = 0; c < 4; ++c)
                *reinterpret_cast<uint4*>(&Vs[nxt][(ve + c * 64) * 40 + vtf]) = vreg[c];
            __syncthreads();
        }
    }

    // epilogue: full row-sum for q=l32 lives split across the two halves
    lsum += __shfl_xor(lsum, 32);
    const float inv = 1.0f / lsum;
    float invr[16];
#pragma unroll
    for (int r = 0; r < 16; ++r)
        invr[r] = __shfl(inv, (r & 3) + 8 * (r >> 2) + 4 * half);

    const int rowb = b * SS + q0 + wave * 32;
#pragma unroll
    for (int et = 0; et < 8; ++et) {
        const int cg = h * 256 + et * 32 + l32;
#pragma unroll
        for (int r = 0; r < 16; ++r) {
            const int row = (r & 3) + 8 * (r >> 2) + 4 * half;
            Cat[(long long)(rowb + row) * (HH * DD) + cg] = f2b(o[et][r] * invr[r]);
        }
    }
}

// ---------------- launch ----------------
extern "C" void kernel_launch(void* const* d_in, const int* in_sizes, int n_in,
                              void* d_out, int out_size, void* d_ws, size_t ws_size,
                              hipStream_t stream)
{
    const float* x   = (const float*)d_in[0];
    const float* Wq  = (const float*)d_in[1];
    const float* bq  = (const float*)d_in[2];
    const float* Wk  = (const float*)d_in[3];
    const float* bk  = (const float*)d_in[4];
    const float* Wv  = (const float*)d_in[5];
    const float* bv  = (const float*)d_in[6];
    const float* Wo  = (const float*)d_in[7];
    const float* bo  = (const float*)d_in[8];
    const float* g1  = (const float*)d_in[9];
    const float* be1 = (const float*)d_in[10];
    const float* g2  = (const float*)d_in[11];
    const float* be2 = (const float*)d_in[12];
    const float* W1  = (const float*)d_in[13];
    const float* bf1 = (const float*)d_in[14];
    const float* W2  = (const float*)d_in[15];
    const float* bf2 = (const float*)d_in[16];
    float* out = (float*)d_out;

    // ---- workspace layout ----
    char* ws = (char*)d_ws;
    unsigned short* xn1  = (unsigned short*)(ws + 0);           // [16384][256] bf16
    unsigned short* qk   = (unsigned short*)(ws + 8388608);     // [16384][2048] bf16 (Q|K by head)
    unsigned short* cat  = (unsigned short*)(ws + 75497472);    // [16384][1024] bf16
    unsigned short* vt   = (unsigned short*)(ws + 109051904);   // [32][256][2048] bf16
    unsigned short* wqkT = (unsigned short*)(ws + 142606336);   // [2048][256] bf16
    unsigned short* wvT  = (unsigned short*)(ws + 143654912);   // [1024][256] bf16
    unsigned short* woT  = (unsigned short*)(ws + 144179200);   // [256][1024] bf16
    unsigned short* w1T  = (unsigned short*)(ws + 144703488);   // [512][256] bf16
    unsigned short* w2T  = (unsigned short*)(ws + 144965632);   // [256][512] bf16
    float*          qkb  = (float*)(ws + 145227776);            // [2048] f32
    float*          vb   = (float*)(ws + 145235968);            // [1024] f32
    // aliases over dead regions:
    float*          xmid = (float*)(ws + 8388608);              // (qk dead after attn)
    unsigned short* xn2  = (unsigned short*)(ws + 25165824);
    unsigned short* mid  = (unsigned short*)(ws + 33554432);

    // fused prologue: all weight transposes + bias concat + LN1 in ONE dispatch
    prologue_kernel<<<dim3(4428), 256, 0, stream>>>(
        Wq, Wk, Wv, Wo, W1, W2, bq, bk, bv, x, g1, be1,
        wqkT, wvT, woT, w1T, w2T, qkb, vb, xn1);

    // fused Q|K projection (2048 blocks)
    gemm_kernel<false, 0, true, 4, false><<<dim3(128, 16), 256, 0, stream>>>(
        xn1, wqkT, qkb, nullptr, qk, MM, 2048, 256);
    // V^T projection straight into vt layout (1024 blocks)
    gemm_kernel<false, 0, true, 4, true><<<dim3(8, 128), 256, 0, stream>>>(
        wvT, xn1, vb, nullptr, vt, 1024, MM, 256);

    // flash attention (32x32 MFMA, 128 q-rows/block, 512 blocks = 2/CU)
    attn_kernel<<<dim3(32, 16), 256, 0, stream>>>(qk, vt, cat);

    // Wo projection + residual(x) -> xmid (f32); 128x64 tiles -> 512 blocks
    gemm_kernel<false, 1, false, 2, false><<<dim3(128, 4), 256, 0, stream>>>(
        cat, woT, bo, x, xmid, MM, 256, 1024);

    // LN2
    ln_kernel<<<dim3(4096), 256, 0, stream>>>(xmid, g2, be2, xn2);

    // FFN1 + ReLU; 128x64 tiles -> 1024 blocks
    gemm_kernel<true, 0, true, 2, false><<<dim3(128, 8), 256, 0, stream>>>(
        xn2, w1T, bf1, nullptr, mid, MM, 512, 256);

    // FFN2 + residual(xmid) -> d_out (f32); 128x64 tiles -> 512 blocks
    gemm_kernel<false, 1, false, 2, false><<<dim3(128, 4), 256, 0, stream>>>(
        mid, w2T, bf2, xmid, out, MM, 256, 512);

    (void)in_sizes; (void)n_in; (void)out_size; (void)ws_size;
}

// Round 10
// 337.863 us; speedup vs baseline: 1.4913x; 1.0251x over previous
//
#include <hip/hip_runtime.h>

typedef __bf16 bf16x8 __attribute__((ext_vector_type(8)));
typedef float  f32x4  __attribute__((ext_vector_type(4)));
typedef float  f32x16 __attribute__((ext_vector_type(16)));

__device__ __forceinline__ unsigned short f2b(float f) {
    union { float f; unsigned int v; } c; c.f = f;
    unsigned int u = c.v;
    unsigned int r = u + 0x7FFFu + ((u >> 16) & 1u);   // RNE
    return (unsigned short)(r >> 16);
}
__device__ __forceinline__ f32x4 mfma16(bf16x8 a, bf16x8 b, f32x4 c) {
    return __builtin_amdgcn_mfma_f32_16x16x32_bf16(a, b, c, 0, 0, 0);
}
__device__ __forceinline__ f32x16 mfma32(bf16x8 a, bf16x8 b, f32x16 c) {
    return __builtin_amdgcn_mfma_f32_32x32x16_bf16(a, b, c, 0, 0, 0);
}
// pack two f32 -> 2xbf16 in one u32 (lo = a, hi = b), RNE
__device__ __forceinline__ unsigned cvtpk(float a, float b) {
    unsigned r;
    asm("v_cvt_pk_bf16_f32 %0, %1, %2" : "=v"(r) : "v"(a), "v"(b));
    return r;
}

// ---------------- constants ----------------
#define BB 8
#define SS 2048
#define DD 256
#define HH 4
#define FF 512
#define MM (BB * SS)   // 16384

// ---------------- fused prologue: 6 weight transposes + bias concat + LN1 ----------------
__device__ __forceinline__ void transpose_body(
    const float* __restrict__ in, unsigned short* __restrict__ out,
    int inS, int outS, int r0, int c0, float scale,
    unsigned short (*T)[72])
{
    const int tid = threadIdx.x;
    const int row = tid >> 3;           // 0..31
    const int col = (tid & 7) * 8;      // 0..56
#pragma unroll
    for (int c = 0; c < 2; ++c) {
        int rr = c * 32 + row;
        const float4 a = *reinterpret_cast<const float4*>(&in[(long long)(r0 + rr) * inS + c0 + col]);
        const float4 b = *reinterpret_cast<const float4*>(&in[(long long)(r0 + rr) * inS + c0 + col + 4]);
        alignas(16) unsigned short t[8] = {
            f2b(a.x * scale), f2b(a.y * scale), f2b(a.z * scale), f2b(a.w * scale),
            f2b(b.x * scale), f2b(b.y * scale), f2b(b.z * scale), f2b(b.w * scale) };
        *reinterpret_cast<uint4*>(&T[rr][col]) = *reinterpret_cast<const uint4*>(t);
    }
    __syncthreads();
#pragma unroll
    for (int c = 0; c < 2; ++c) {
        int orow = c * 32 + row;
        alignas(16) unsigned short tmp[8];
#pragma unroll
        for (int j = 0; j < 8; ++j) tmp[j] = T[col + j][orow];
        *reinterpret_cast<uint4*>(&out[(long long)(c0 + orow) * outS + r0 + col]) =
            *reinterpret_cast<const uint4*>(tmp);
    }
}

__global__ __launch_bounds__(256) void prologue_kernel(
    const float* __restrict__ Wq, const float* __restrict__ Wk,
    const float* __restrict__ Wv, const float* __restrict__ Wo,
    const float* __restrict__ W1, const float* __restrict__ W2,
    const float* __restrict__ bq, const float* __restrict__ bk,
    const float* __restrict__ bv,
    const float* __restrict__ x,  const float* __restrict__ g1,
    const float* __restrict__ be1,
    unsigned short* __restrict__ wqkT, unsigned short* __restrict__ wvT,
    unsigned short* __restrict__ woT,  unsigned short* __restrict__ w1T,
    unsigned short* __restrict__ w2T,
    float* __restrict__ qkb, float* __restrict__ vb,
    unsigned short* __restrict__ xn1)
{
    __shared__ unsigned short T[64][72];
    const int blk = blockIdx.x;
    if (blk < 320) {
        const float* in; unsigned short* out; int inS, outS, r0, c0; float scale;
        if (blk < 192) {                       // Wq | Wk | Wv : per-head 256x256
            const int w = blk >> 6;            // 0,1,2
            const int b = blk & 63;
            const int z = b >> 4;              // head
            in  = (w == 0 ? Wq : w == 1 ? Wk : Wv) + z * 65536;
            out = (w == 0 ? wqkT : w == 1 ? wqkT + 262144 : wvT) + z * 65536;
            inS = 256; outS = 256; scale = (w == 0) ? 0.0625f : 1.0f;
            r0 = (b & 3) * 64; c0 = ((b >> 2) & 3) * 64;
        } else if (blk < 256) {                // Wo: 1024x256 -> 256x1024
            const int b = blk - 192;
            in = Wo; out = woT; inS = 256; outS = 1024; scale = 1.0f;
            r0 = (b & 15) * 64; c0 = (b >> 4) * 64;
        } else if (blk < 288) {                // W1: 256x512 -> 512x256
            const int b = blk - 256;
            in = W1; out = w1T; inS = 512; outS = 256; scale = 1.0f;
            r0 = (b & 3) * 64; c0 = (b >> 2) * 64;
        } else {                               // W2: 512x256 -> 256x512
            const int b = blk - 288;
            in = W2; out = w2T; inS = 256; outS = 512; scale = 1.0f;
            r0 = (b & 7) * 64; c0 = (b >> 3) * 64;
        }
        transpose_body(in, out, inS, outS, r0, c0, scale, T);
    } else if (blk < 332) {                    // bias concat
        const int i = (blk - 320) * 256 + threadIdx.x;
        if (i < 1024)       qkb[i] = bq[i] * 0.0625f;
        else if (i < 2048)  qkb[i] = bk[i - 1024];
        else                vb[i - 2048] = bv[i - 2048];
    } else {                                   // LN1, 4 rows/block
        const int tid  = threadIdx.x;
        const int wave = tid >> 6, lane = tid & 63;
        const int row  = (blk - 332) * 4 + wave;
        const float4 v = reinterpret_cast<const float4*>(x)[(long long)row * 64 + lane];
        float xr[4] = { v.x, v.y, v.z, v.w };
        float s = xr[0] + xr[1] + xr[2] + xr[3];
        float q = xr[0]*xr[0] + xr[1]*xr[1] + xr[2]*xr[2] + xr[3]*xr[3];
#pragma unroll
        for (int off = 1; off < 64; off <<= 1) {
            s += __shfl_xor(s, off);
            q += __shfl_xor(q, off);
        }
        const float mean = s * (1.0f / 256.0f);
        const float var  = q * (1.0f / 256.0f) - mean * mean;
        const float rs   = rsqrtf(var + 1e-5f);
        const float4 gv = reinterpret_cast<const float4*>(g1)[lane];
        const float4 bv4 = reinterpret_cast<const float4*>(be1)[lane];
        unsigned short y[4];
        y[0] = f2b((xr[0] - mean) * rs * gv.x + bv4.x);
        y[1] = f2b((xr[1] - mean) * rs * gv.y + bv4.y);
        y[2] = f2b((xr[2] - mean) * rs * gv.z + bv4.z);
        y[3] = f2b((xr[3] - mean) * rs * gv.w + bv4.w);
        uint2 o;
        o.x = (unsigned int)y[0] | ((unsigned int)y[1] << 16);
        o.y = (unsigned int)y[2] | ((unsigned int)y[3] << 16);
        reinterpret_cast<uint2*>(xn1)[(long long)row * 64 + lane] = o;
    }
}

// ---------------- LayerNorm: one wave per 256-elem row, f32 in -> bf16 out ----------------
__global__ __launch_bounds__(256) void ln_kernel(
    const float* __restrict__ in, const float* __restrict__ g,
    const float* __restrict__ bta, unsigned short* __restrict__ out)
{
    const int tid  = threadIdx.x;
    const int wave = tid >> 6, lane = tid & 63;
    const int row  = blockIdx.x * 4 + wave;
    const float4 v = reinterpret_cast<const float4*>(in)[(long long)row * 64 + lane];
    float x[4] = { v.x, v.y, v.z, v.w };
    float s = x[0] + x[1] + x[2] + x[3];
    float q = x[0]*x[0] + x[1]*x[1] + x[2]*x[2] + x[3]*x[3];
#pragma unroll
    for (int off = 1; off < 64; off <<= 1) {
        s += __shfl_xor(s, off);
        q += __shfl_xor(q, off);
    }
    const float mean = s * (1.0f / 256.0f);
    const float var  = q * (1.0f / 256.0f) - mean * mean;
    const float rs   = rsqrtf(var + 1e-5f);
    const float4 gv = reinterpret_cast<const float4*>(g)[lane];
    const float4 bv = reinterpret_cast<const float4*>(bta)[lane];
    unsigned short y[4];
    y[0] = f2b((x[0] - mean) * rs * gv.x + bv.x);
    y[1] = f2b((x[1] - mean) * rs * gv.y + bv.y);
    y[2] = f2b((x[2] - mean) * rs * gv.z + bv.z);
    y[3] = f2b((x[3] - mean) * rs * gv.w + bv.w);
    uint2 o;
    o.x = (unsigned int)y[0] | ((unsigned int)y[1] << 16);
    o.y = (unsigned int)y[2] | ((unsigned int)y[3] << 16);
    reinterpret_cast<uint2*>(out)[(long long)row * 64 + lane] = o;
}

// ---------------- GEMM body: C[MxN] = A[MxK] @ B  (B given as BT[N x K], bf16) ----------------
// Round-1 structure: single-buffer LDS, fused global-load -> LDS-write staging, 2 barriers
// per BK-step. BK=64 halves the latency-exposed iteration count for small-grid GEMMs
// (LDS 27.6KB still allows 5 blocks/CU >= those grids' 2-4). No persistent staging regs
// (reg-prefetch regressed twice: r7/r8, occupancy/TLP loss).
template <bool RELU, int RES, bool OUTBF, int NS, bool VT, int BK>
__device__ __forceinline__ void gemm_body(
    unsigned short* __restrict__ As, unsigned short* __restrict__ Bs,
    const unsigned short* __restrict__ A, const unsigned short* __restrict__ BT,
    const float* __restrict__ bias, const float* __restrict__ res,
    void* __restrict__ out, int M, int N, int K, int bx, int by)
{
    constexpr int LDW = BK + 8;                    // 40 or 72 (both conflict-free)
    const int tid  = threadIdx.x;
    const int wave = tid >> 6, lane = tid & 63;
    const int quad = lane >> 4, l16 = lane & 15;
    const int wm = wave >> 1, wn = wave & 1;
    const int WN = NS * 16;                        // wave n-width
    const int m0 = bx * 128, n0 = by * (2 * WN);

    f32x4 acc[4][NS];
#pragma unroll
    for (int i = 0; i < 4; ++i)
#pragma unroll
        for (int j = 0; j < NS; ++j) acc[i][j] = (f32x4){0.f, 0.f, 0.f, 0.f};

    const int srow = tid >> 2;          // 0..63
    const int scol = (tid & 3) * 8;     // 0,8,16,24

    for (int k0 = 0; k0 < K; k0 += BK) {
        __syncthreads();
#pragma unroll
        for (int cc = 0; cc < BK / 32; ++cc) {
#pragma unroll
            for (int c = 0; c < 2; ++c) {
                const int r = c * 64 + srow;
                *reinterpret_cast<uint4*>(&As[r * LDW + cc * 32 + scol]) =
                    *reinterpret_cast<const uint4*>(&A[(long long)(m0 + r) * K + k0 + cc * 32 + scol]);
            }
            *reinterpret_cast<uint4*>(&Bs[srow * LDW + cc * 32 + scol]) =
                *reinterpret_cast<const uint4*>(&BT[(long long)(n0 + srow) * K + k0 + cc * 32 + scol]);
            if (NS == 4) {
                const int r = 64 + srow;
                *reinterpret_cast<uint4*>(&Bs[r * LDW + cc * 32 + scol]) =
                    *reinterpret_cast<const uint4*>(&BT[(long long)(n0 + r) * K + k0 + cc * 32 + scol]);
            }
        }
        __syncthreads();
#pragma unroll
        for (int kk = 0; kk < BK / 32; ++kk) {
            bf16x8 af[4], bf[NS];
#pragma unroll
            for (int ms = 0; ms < 4; ++ms)
                af[ms] = *reinterpret_cast<const bf16x8*>(&As[(wm * 64 + ms * 16 + l16) * LDW + kk * 32 + quad * 8]);
#pragma unroll
            for (int ns = 0; ns < NS; ++ns)
                bf[ns] = *reinterpret_cast<const bf16x8*>(&Bs[(wn * WN + ns * 16 + l16) * LDW + kk * 32 + quad * 8]);
#pragma unroll
            for (int ms = 0; ms < 4; ++ms)
#pragma unroll
                for (int ns = 0; ns < NS; ++ns)
                    acc[ms][ns] = mfma16(af[ms], bf[ns], acc[ms][ns]);
        }
    }

    // epilogue (round-1 layout: col = l16, rows = quad*4+r)
#pragma unroll
    for (int ms = 0; ms < 4; ++ms) {
#pragma unroll
        for (int ns = 0; ns < NS; ++ns) {
            const int cg = n0 + wn * WN + ns * 16 + l16;
            const float bvc = VT ? 0.f : bias[cg];
#pragma unroll
            for (int r = 0; r < 4; ++r) {
                const int rg = m0 + wm * 64 + ms * 16 + quad * 4 + r;
                float v = acc[ms][ns][r] + (VT ? bias[rg] : bvc);
                if (RELU)   v = fmaxf(v, 0.0f);
                if (RES == 1)
                    v += res[(long long)rg * N + cg];
                if (VT) {
                    // rg = h*256+e (M=1024), cg = b*2048+t (N=16384) -> vt[(b*4+h)][e][t]
                    const long long oaddr =
                        (long long)((cg >> 11) * 4 + (rg >> 8)) * 524288 +
                        (long long)(rg & 255) * 2048 + (cg & 2047);
                    reinterpret_cast<unsigned short*>(out)[oaddr] = f2b(v);
                } else if (OUTBF) {
                    reinterpret_cast<unsigned short*>(out)[(long long)rg * N + cg] = f2b(v);
                } else {
                    reinterpret_cast<float*>(out)[(long long)rg * N + cg] = v;
                }
            }
        }
    }
}

template <bool RELU, int RES, bool OUTBF, int NS, bool VT, int BK>
__global__ __launch_bounds__(256) void gemm_kernel(
    const unsigned short* __restrict__ A, const unsigned short* __restrict__ BT,
    const float* __restrict__ bias, const float* __restrict__ res,
    void* __restrict__ out, int M, int N, int K)
{
    __shared__ unsigned short As[128 * (BK + 8)];
    __shared__ unsigned short Bs[(NS == 4 ? 128 : 64) * (BK + 8)];
    gemm_body<RELU, RES, OUTBF, NS, VT, BK>(As, Bs, A, BT, bias, res, out,
                                            M, N, K, blockIdx.x, blockIdx.y);
}

// merged QK-proj (blocks 0..2047) + V-proj (2048..3071): independent, same geometry
__global__ __launch_bounds__(256) void qkv_kernel(
    const unsigned short* __restrict__ xn1, const unsigned short* __restrict__ wqkT,
    const unsigned short* __restrict__ wvT,
    const float* __restrict__ qkb, const float* __restrict__ vb,
    unsigned short* __restrict__ qk, unsigned short* __restrict__ vt)
{
    __shared__ unsigned short As[128 * 40];
    __shared__ unsigned short Bs[128 * 40];
    const int bid = blockIdx.x;
    if (bid < 2048) {
        gemm_body<false, 0, true, 4, false, 32>(As, Bs, xn1, wqkT, qkb, nullptr, qk,
                                                MM, 2048, 256, bid & 127, bid >> 7);
    } else {
        const int b2 = bid - 2048;
        gemm_body<false, 0, true, 4, true, 32>(As, Bs, wvT, xn1, vb, nullptr, vt,
                                               1024, MM, 256, b2 & 7, b2 >> 3);
    }
}

// ---------------- Flash attention (round-1 exact: 139.6-152 us band) ----------------
// K and V double-buffered in LDS via reg staging; in-register P (swapped QK^T + cvt_pk +
// permlane32_swap); split sc chains; __expf softmax; 1 barrier/iter.
// LDS: 2*(32*264 + 256*40)*2B = 74752 B -> 2 blocks/CU. ~90% of LDS-port roofline.
__global__ __launch_bounds__(256, 2) void attn_kernel(
    const unsigned short* __restrict__ QK, const unsigned short* __restrict__ Vt,
    unsigned short* __restrict__ Cat)
{
    __shared__ __align__(16) unsigned short Ks[2][32 * 264];   // [t][d], stride 264
    __shared__ __align__(16) unsigned short Vs[2][256 * 40];   // [e][t], stride 40
    const int tid  = threadIdx.x;
    const int wave = tid >> 6, lane = tid & 63;
    const int l32 = lane & 31, half = lane >> 5;
    const int by = blockIdx.x;              // b*4 + h
    const int h = by & 3, b = by >> 2;
    const int q0 = blockIdx.y * 128;
    const unsigned short* Qb = QK + (long long)b * SS * 2048 + h * 256;
    const unsigned short* Kb = Qb + 1024;
    const unsigned short* vbase = Vt + (long long)by * DD * SS;

    // Q fragments, 32 rows/wave: lane holds Q[q0+w*32+l32][kb*16 + half*8 + j]
    bf16x8 qf[16];
    {
        const unsigned short* qrow = Qb + (long long)(q0 + wave * 32 + l32) * 2048 + half * 8;
#pragma unroll
        for (int kb = 0; kb < 16; ++kb)
            qf[kb] = *reinterpret_cast<const bf16x8*>(qrow + kb * 16);
    }

    f32x16 o[8];
#pragma unroll
    for (int i = 0; i < 8; ++i)
#pragma unroll
        for (int r = 0; r < 16; ++r) o[i][r] = 0.f;
    float lsum = 0.f;   // per-lane partial row-sum for q = l32 (this half's t-subset)

    const int krow = tid >> 3;          // 0..31
    const int kcol = (tid & 7) * 8;     // 0..56 (shorts)
    const int ve   = tid >> 2;          // 0..63 (base V row)
    const int vtf  = (tid & 3) * 8;     // 0..24 (t offset, shorts)

    uint4 kreg[4], vreg[4];
    // prologue: stage tile 0 into buffer 0
#pragma unroll
    for (int c = 0; c < 4; ++c)
        kreg[c] = *reinterpret_cast<const uint4*>(&Kb[(long long)krow * 2048 + kcol + c * 64]);
#pragma unroll
    for (int c = 0; c < 4; ++c)
        vreg[c] = *reinterpret_cast<const uint4*>(&vbase[(long long)(ve + c * 64) * SS + vtf]);
#pragma unroll
    for (int c = 0; c < 4; ++c)
        *reinterpret_cast<uint4*>(&Ks[0][krow * 264 + kcol + c * 64]) = kreg[c];
#pragma unroll
    for (int c = 0; c < 4; ++c)
        *reinterpret_cast<uint4*>(&Vs[0][(ve + c * 64) * 40 + vtf]) = vreg[c];
    __syncthreads();

    for (int t = 0; t < 64; ++t) {
        const int cur = t & 1;
        // issue next-tile global loads early (latency hides under compute)
        if (t < 63) {
            const int t1 = (t + 1) * 32;
#pragma unroll
            for (int c = 0; c < 4; ++c)
                kreg[c] = *reinterpret_cast<const uint4*>(&Kb[(long long)(t1 + krow) * 2048 + kcol + c * 64]);
#pragma unroll
            for (int c = 0; c < 4; ++c)
                vreg[c] = *reinterpret_cast<const uint4*>(&vbase[(long long)(ve + c * 64) * SS + t1 + vtf]);
        }

        // swapped QK^T: sc = K_tile . Q^T -> lane holds S[q=l32][t-subset], split acc chain
        f32x16 sc0, sc1;
#pragma unroll
        for (int r = 0; r < 16; ++r) { sc0[r] = 0.f; sc1[r] = 0.f; }
        __builtin_amdgcn_s_setprio(1);
#pragma unroll
        for (int kb = 0; kb < 8; ++kb) {
            bf16x8 kf0 = *reinterpret_cast<const bf16x8*>(&Ks[cur][l32 * 264 + (2 * kb) * 16 + half * 8]);
            bf16x8 kf1 = *reinterpret_cast<const bf16x8*>(&Ks[cur][l32 * 264 + (2 * kb + 1) * 16 + half * 8]);
            sc0 = mfma32(kf0, qf[2 * kb], sc0);
            sc1 = mfma32(kf1, qf[2 * kb + 1], sc1);
        }
        __builtin_amdgcn_s_setprio(0);

        // softmax numerator: p = exp(s); accumulate row-sums per lane
        float p[16];
#pragma unroll
        for (int r = 0; r < 16; ++r) {
            p[r] = __expf(sc0[r] + sc1[r]);
            lsum += p[r];
        }

        // pack P -> PV A-fragments fully in-register (cvt_pk + permlane32_swap)
        unsigned pk[8];
#pragma unroll
        for (int i = 0; i < 8; ++i) pk[i] = cvtpk(p[2 * i], p[2 * i + 1]);
        union { bf16x8 v; unsigned u[4]; } A0, A1;   // A0: t=0..15, A1: t=16..31
        { auto rr = __builtin_amdgcn_permlane32_swap(pk[0], pk[2], false, false); A0.u[0] = rr[0]; A0.u[2] = rr[1]; }
        { auto rr = __builtin_amdgcn_permlane32_swap(pk[1], pk[3], false, false); A0.u[1] = rr[0]; A0.u[3] = rr[1]; }
        { auto rr = __builtin_amdgcn_permlane32_swap(pk[4], pk[6], false, false); A1.u[0] = rr[0]; A1.u[2] = rr[1]; }
        { auto rr = __builtin_amdgcn_permlane32_swap(pk[5], pk[7], false, false); A1.u[1] = rr[0]; A1.u[3] = rr[1]; }

        // PV: B = V^T tile from Vs; 8 e-tiles x 2 k-steps
        __builtin_amdgcn_s_setprio(1);
#pragma unroll
        for (int et = 0; et < 8; ++et) {
            bf16x8 vf0 = *reinterpret_cast<const bf16x8*>(&Vs[cur][(et * 32 + l32) * 40 + half * 8]);
            bf16x8 vf1 = *reinterpret_cast<const bf16x8*>(&Vs[cur][(et * 32 + l32) * 40 + 16 + half * 8]);
            o[et] = mfma32(A0.v, vf0, o[et]);
            o[et] = mfma32(A1.v, vf1, o[et]);
        }
        __builtin_amdgcn_s_setprio(0);

        // write next tile into the other buffer, then single barrier
        if (t < 63) {
            const int nxt = cur ^ 1;
#pragma unroll
            for (int c = 0; c < 4; ++c)
                *reinterpret_cast<uint4*>(&Ks[nxt][krow * 264 + kcol + c * 64]) = kreg[c];
#pragma unroll
            for (int c = 0; c < 4; ++c)
                *reinterpret_cast<uint4*>(&Vs[nxt][(ve + c * 64) * 40 + vtf]) = vreg[c];
            __syncthreads();
        }
    }

    // epilogue: full row-sum for q=l32 lives split across the two halves
    lsum += __shfl_xor(lsum, 32);
    const float inv = 1.0f / lsum;
    float invr[16];
#pragma unroll
    for (int r = 0; r < 16; ++r)
        invr[r] = __shfl(inv, (r & 3) + 8 * (r >> 2) + 4 * half);

    const int rowb = b * SS + q0 + wave * 32;
#pragma unroll
    for (int et = 0; et < 8; ++et) {
        const int cg = h * 256 + et * 32 + l32;
#pragma unroll
        for (int r = 0; r < 16; ++r) {
            const int row = (r & 3) + 8 * (r >> 2) + 4 * half;
            Cat[(long long)(rowb + row) * (HH * DD) + cg] = f2b(o[et][r] * invr[r]);
        }
    }
}

// ---------------- launch ----------------
extern "C" void kernel_launch(void* const* d_in, const int* in_sizes, int n_in,
                              void* d_out, int out_size, void* d_ws, size_t ws_size,
                              hipStream_t stream)
{
    const float* x   = (const float*)d_in[0];
    const float* Wq  = (const float*)d_in[1];
    const float* bq  = (const float*)d_in[2];
    const float* Wk  = (const float*)d_in[3];
    const float* bk  = (const float*)d_in[4];
    const float* Wv  = (const float*)d_in[5];
    const float* bv  = (const float*)d_in[6];
    const float* Wo  = (const float*)d_in[7];
    const float* bo  = (const float*)d_in[8];
    const float* g1  = (const float*)d_in[9];
    const float* be1 = (const float*)d_in[10];
    const float* g2  = (const float*)d_in[11];
    const float* be2 = (const float*)d_in[12];
    const float* W1  = (const float*)d_in[13];
    const float* bf1 = (const float*)d_in[14];
    const float* W2  = (const float*)d_in[15];
    const float* bf2 = (const float*)d_in[16];
    float* out = (float*)d_out;

    // ---- workspace layout ----
    char* ws = (char*)d_ws;
    unsigned short* xn1  = (unsigned short*)(ws + 0);           // [16384][256] bf16
    unsigned short* qk   = (unsigned short*)(ws + 8388608);     // [16384][2048] bf16 (Q|K by head)
    unsigned short* cat  = (unsigned short*)(ws + 75497472);    // [16384][1024] bf16
    unsigned short* vt   = (unsigned short*)(ws + 109051904);   // [32][256][2048] bf16
    unsigned short* wqkT = (unsigned short*)(ws + 142606336);   // [2048][256] bf16
    unsigned short* wvT  = (unsigned short*)(ws + 143654912);   // [1024][256] bf16
    unsigned short* woT  = (unsigned short*)(ws + 144179200);   // [256][1024] bf16
    unsigned short* w1T  = (unsigned short*)(ws + 144703488);   // [512][256] bf16
    unsigned short* w2T  = (unsigned short*)(ws + 144965632);   // [256][512] bf16
    float*          qkb  = (float*)(ws + 145227776);            // [2048] f32
    float*          vb   = (float*)(ws + 145235968);            // [1024] f32
    // aliases over dead regions:
    float*          xmid = (float*)(ws + 8388608);              // (qk dead after attn)
    unsigned short* xn2  = (unsigned short*)(ws + 25165824);
    unsigned short* mid  = (unsigned short*)(ws + 33554432);

    // fused prologue: all weight transposes + bias concat + LN1 in ONE dispatch
    prologue_kernel<<<dim3(4428), 256, 0, stream>>>(
        Wq, Wk, Wv, Wo, W1, W2, bq, bk, bv, x, g1, be1,
        wqkT, wvT, woT, w1T, w2T, qkb, vb, xn1);

    // merged Q|K projection + V^T projection (3072 blocks, one dispatch)
    qkv_kernel<<<dim3(3072), 256, 0, stream>>>(xn1, wqkT, wvT, qkb, vb, qk, vt);

    // flash attention (32x32 MFMA, 128 q-rows/block, 512 blocks = 2/CU)
    attn_kernel<<<dim3(32, 16), 256, 0, stream>>>(qk, vt, cat);

    // Wo projection + residual(x) -> xmid (f32); BK=64 (16 iters), 512 blocks
    gemm_kernel<false, 1, false, 2, false, 64><<<dim3(128, 4), 256, 0, stream>>>(
        cat, woT, bo, x, xmid, MM, 256, 1024);

    // LN2
    ln_kernel<<<dim3(4096), 256, 0, stream>>>(xmid, g2, be2, xn2);

    // FFN1 + ReLU; BK=64 (4 iters), 1024 blocks
    gemm_kernel<true, 0, true, 2, false, 64><<<dim3(128, 8), 256, 0, stream>>>(
        xn2, w1T, bf1, nullptr, mid, MM, 512, 256);

    // FFN2 + residual(xmid) -> d_out (f32); BK=64 (8 iters), 512 blocks
    gemm_kernel<false, 1, false, 2, false, 64><<<dim3(128, 4), 256, 0, stream>>>(
        mid, w2T, bf2, xmid, out, MM, 256, 512);

    (void)in_sizes; (void)n_in; (void)out_size; (void)ws_size;
}

// Round 11
// 330.644 us; speedup vs baseline: 1.5239x; 1.0218x over previous
//
#include <hip/hip_runtime.h>

typedef __bf16 bf16x8 __attribute__((ext_vector_type(8)));
typedef float  f32x4  __attribute__((ext_vector_type(4)));
typedef float  f32x16 __attribute__((ext_vector_type(16)));

__device__ __forceinline__ unsigned short f2b(float f) {
    union { float f; unsigned int v; } c; c.f = f;
    unsigned int u = c.v;
    unsigned int r = u + 0x7FFFu + ((u >> 16) & 1u);   // RNE
    return (unsigned short)(r >> 16);
}
__device__ __forceinline__ f32x4 mfma16(bf16x8 a, bf16x8 b, f32x4 c) {
    return __builtin_amdgcn_mfma_f32_16x16x32_bf16(a, b, c, 0, 0, 0);
}
__device__ __forceinline__ f32x16 mfma32(bf16x8 a, bf16x8 b, f32x16 c) {
    return __builtin_amdgcn_mfma_f32_32x32x16_bf16(a, b, c, 0, 0, 0);
}
// pack two f32 -> 2xbf16 in one u32 (lo = a, hi = b), RNE
__device__ __forceinline__ unsigned cvtpk(float a, float b) {
    unsigned r;
    asm("v_cvt_pk_bf16_f32 %0, %1, %2" : "=v"(r) : "v"(a), "v"(b));
    return r;
}

// ---------------- constants ----------------
#define BB 8
#define SS 2048
#define DD 256
#define HH 4
#define FF 512
#define MM (BB * SS)   // 16384

// ---------------- fused prologue: 6 weight transposes + bias concat + LN1 ----------------
__device__ __forceinline__ void transpose_body(
    const float* __restrict__ in, unsigned short* __restrict__ out,
    int inS, int outS, int r0, int c0, float scale,
    unsigned short (*T)[72])
{
    const int tid = threadIdx.x;
    const int row = tid >> 3;           // 0..31
    const int col = (tid & 7) * 8;      // 0..56
#pragma unroll
    for (int c = 0; c < 2; ++c) {
        int rr = c * 32 + row;
        const float4 a = *reinterpret_cast<const float4*>(&in[(long long)(r0 + rr) * inS + c0 + col]);
        const float4 b = *reinterpret_cast<const float4*>(&in[(long long)(r0 + rr) * inS + c0 + col + 4]);
        alignas(16) unsigned short t[8] = {
            f2b(a.x * scale), f2b(a.y * scale), f2b(a.z * scale), f2b(a.w * scale),
            f2b(b.x * scale), f2b(b.y * scale), f2b(b.z * scale), f2b(b.w * scale) };
        *reinterpret_cast<uint4*>(&T[rr][col]) = *reinterpret_cast<const uint4*>(t);
    }
    __syncthreads();
#pragma unroll
    for (int c = 0; c < 2; ++c) {
        int orow = c * 32 + row;
        alignas(16) unsigned short tmp[8];
#pragma unroll
        for (int j = 0; j < 8; ++j) tmp[j] = T[col + j][orow];
        *reinterpret_cast<uint4*>(&out[(long long)(c0 + orow) * outS + r0 + col]) =
            *reinterpret_cast<const uint4*>(tmp);
    }
}

__global__ __launch_bounds__(256) void prologue_kernel(
    const float* __restrict__ Wq, const float* __restrict__ Wk,
    const float* __restrict__ Wv, const float* __restrict__ Wo,
    const float* __restrict__ W1, const float* __restrict__ W2,
    const float* __restrict__ bq, const float* __restrict__ bk,
    const float* __restrict__ bv,
    const float* __restrict__ x,  const float* __restrict__ g1,
    const float* __restrict__ be1,
    unsigned short* __restrict__ wqkT, unsigned short* __restrict__ wvT,
    unsigned short* __restrict__ woT,  unsigned short* __restrict__ w1T,
    unsigned short* __restrict__ w2T,
    float* __restrict__ qkb, float* __restrict__ vb,
    unsigned short* __restrict__ xn1)
{
    __shared__ unsigned short T[64][72];
    const int blk = blockIdx.x;
    if (blk < 320) {
        const float* in; unsigned short* out; int inS, outS, r0, c0; float scale;
        if (blk < 192) {                       // Wq | Wk | Wv : per-head 256x256
            const int w = blk >> 6;            // 0,1,2
            const int b = blk & 63;
            const int z = b >> 4;              // head
            in  = (w == 0 ? Wq : w == 1 ? Wk : Wv) + z * 65536;
            out = (w == 0 ? wqkT : w == 1 ? wqkT + 262144 : wvT) + z * 65536;
            inS = 256; outS = 256; scale = (w == 0) ? 0.0625f : 1.0f;
            r0 = (b & 3) * 64; c0 = ((b >> 2) & 3) * 64;
        } else if (blk < 256) {                // Wo: 1024x256 -> 256x1024
            const int b = blk - 192;
            in = Wo; out = woT; inS = 256; outS = 1024; scale = 1.0f;
            r0 = (b & 15) * 64; c0 = (b >> 4) * 64;
        } else if (blk < 288) {                // W1: 256x512 -> 512x256
            const int b = blk - 256;
            in = W1; out = w1T; inS = 512; outS = 256; scale = 1.0f;
            r0 = (b & 3) * 64; c0 = (b >> 2) * 64;
        } else {                               // W2: 512x256 -> 256x512
            const int b = blk - 288;
            in = W2; out = w2T; inS = 256; outS = 512; scale = 1.0f;
            r0 = (b & 7) * 64; c0 = (b >> 3) * 64;
        }
        transpose_body(in, out, inS, outS, r0, c0, scale, T);
    } else if (blk < 332) {                    // bias concat
        const int i = (blk - 320) * 256 + threadIdx.x;
        if (i < 1024)       qkb[i] = bq[i] * 0.0625f;
        else if (i < 2048)  qkb[i] = bk[i - 1024];
        else                vb[i - 2048] = bv[i - 2048];
    } else {                                   // LN1, 4 rows/block
        const int tid  = threadIdx.x;
        const int wave = tid >> 6, lane = tid & 63;
        const int row  = (blk - 332) * 4 + wave;
        const float4 v = reinterpret_cast<const float4*>(x)[(long long)row * 64 + lane];
        float xr[4] = { v.x, v.y, v.z, v.w };
        float s = xr[0] + xr[1] + xr[2] + xr[3];
        float q = xr[0]*xr[0] + xr[1]*xr[1] + xr[2]*xr[2] + xr[3]*xr[3];
#pragma unroll
        for (int off = 1; off < 64; off <<= 1) {
            s += __shfl_xor(s, off);
            q += __shfl_xor(q, off);
        }
        const float mean = s * (1.0f / 256.0f);
        const float var  = q * (1.0f / 256.0f) - mean * mean;
        const float rs   = rsqrtf(var + 1e-5f);
        const float4 gv = reinterpret_cast<const float4*>(g1)[lane];
        const float4 bv4 = reinterpret_cast<const float4*>(be1)[lane];
        unsigned short y[4];
        y[0] = f2b((xr[0] - mean) * rs * gv.x + bv4.x);
        y[1] = f2b((xr[1] - mean) * rs * gv.y + bv4.y);
        y[2] = f2b((xr[2] - mean) * rs * gv.z + bv4.z);
        y[3] = f2b((xr[3] - mean) * rs * gv.w + bv4.w);
        uint2 o;
        o.x = (unsigned int)y[0] | ((unsigned int)y[1] << 16);
        o.y = (unsigned int)y[2] | ((unsigned int)y[3] << 16);
        reinterpret_cast<uint2*>(xn1)[(long long)row * 64 + lane] = o;
    }
}

// ---------------- LayerNorm: one wave per 256-elem row, f32 in -> bf16 out ----------------
__global__ __launch_bounds__(256) void ln_kernel(
    const float* __restrict__ in, const float* __restrict__ g,
    const float* __restrict__ bta, unsigned short* __restrict__ out)
{
    const int tid  = threadIdx.x;
    const int wave = tid >> 6, lane = tid & 63;
    const int row  = blockIdx.x * 4 + wave;
    const float4 v = reinterpret_cast<const float4*>(in)[(long long)row * 64 + lane];
    float x[4] = { v.x, v.y, v.z, v.w };
    float s = x[0] + x[1] + x[2] + x[3];
    float q = x[0]*x[0] + x[1]*x[1] + x[2]*x[2] + x[3]*x[3];
#pragma unroll
    for (int off = 1; off < 64; off <<= 1) {
        s += __shfl_xor(s, off);
        q += __shfl_xor(q, off);
    }
    const float mean = s * (1.0f / 256.0f);
    const float var  = q * (1.0f / 256.0f) - mean * mean;
    const float rs   = rsqrtf(var + 1e-5f);
    const float4 gv = reinterpret_cast<const float4*>(g)[lane];
    const float4 bv = reinterpret_cast<const float4*>(bta)[lane];
    unsigned short y[4];
    y[0] = f2b((x[0] - mean) * rs * gv.x + bv.x);
    y[1] = f2b((x[1] - mean) * rs * gv.y + bv.y);
    y[2] = f2b((x[2] - mean) * rs * gv.z + bv.z);
    y[3] = f2b((x[3] - mean) * rs * gv.w + bv.w);
    uint2 o;
    o.x = (unsigned int)y[0] | ((unsigned int)y[1] << 16);
    o.y = (unsigned int)y[2] | ((unsigned int)y[3] << 16);
    reinterpret_cast<uint2*>(out)[(long long)row * 64 + lane] = o;
}

// ---------------- GEMM body: C[MxN] = A[MxK] @ B  (B given as BT[N x K], bf16) ----------------
// Round-1 structure: single-buffer LDS, fused global-load -> LDS-write staging, 2 barriers
// per BK-step. BK sized per-dispatch so LDS blocks/CU >= the grid's blocks/CU (occupancy
// never reduced). No persistent staging regs (reg-prefetch regressed twice: r7/r8).
template <bool RELU, int RES, bool OUTBF, int NS, bool VT, int BK>
__device__ __forceinline__ void gemm_body(
    unsigned short* __restrict__ As, unsigned short* __restrict__ Bs,
    const unsigned short* __restrict__ A, const unsigned short* __restrict__ BT,
    const float* __restrict__ bias, const float* __restrict__ res,
    void* __restrict__ out, int M, int N, int K, int bx, int by)
{
    constexpr int LDW = BK + 8;                    // 40/72/136 (all ≡4 mod 32 dwords: conflict-free)
    const int tid  = threadIdx.x;
    const int wave = tid >> 6, lane = tid & 63;
    const int quad = lane >> 4, l16 = lane & 15;
    const int wm = wave >> 1, wn = wave & 1;
    const int WN = NS * 16;                        // wave n-width
    const int m0 = bx * 128, n0 = by * (2 * WN);

    f32x4 acc[4][NS];
#pragma unroll
    for (int i = 0; i < 4; ++i)
#pragma unroll
        for (int j = 0; j < NS; ++j) acc[i][j] = (f32x4){0.f, 0.f, 0.f, 0.f};

    const int srow = tid >> 2;          // 0..63
    const int scol = (tid & 3) * 8;     // 0,8,16,24

    for (int k0 = 0; k0 < K; k0 += BK) {
        __syncthreads();
#pragma unroll
        for (int cc = 0; cc < BK / 32; ++cc) {
#pragma unroll
            for (int c = 0; c < 2; ++c) {
                const int r = c * 64 + srow;
                *reinterpret_cast<uint4*>(&As[r * LDW + cc * 32 + scol]) =
                    *reinterpret_cast<const uint4*>(&A[(long long)(m0 + r) * K + k0 + cc * 32 + scol]);
            }
            *reinterpret_cast<uint4*>(&Bs[srow * LDW + cc * 32 + scol]) =
                *reinterpret_cast<const uint4*>(&BT[(long long)(n0 + srow) * K + k0 + cc * 32 + scol]);
            if (NS == 4) {
                const int r = 64 + srow;
                *reinterpret_cast<uint4*>(&Bs[r * LDW + cc * 32 + scol]) =
                    *reinterpret_cast<const uint4*>(&BT[(long long)(n0 + r) * K + k0 + cc * 32 + scol]);
            }
        }
        __syncthreads();
#pragma unroll
        for (int kk = 0; kk < BK / 32; ++kk) {
            bf16x8 af[4], bf[NS];
#pragma unroll
            for (int ms = 0; ms < 4; ++ms)
                af[ms] = *reinterpret_cast<const bf16x8*>(&As[(wm * 64 + ms * 16 + l16) * LDW + kk * 32 + quad * 8]);
#pragma unroll
            for (int ns = 0; ns < NS; ++ns)
                bf[ns] = *reinterpret_cast<const bf16x8*>(&Bs[(wn * WN + ns * 16 + l16) * LDW + kk * 32 + quad * 8]);
#pragma unroll
            for (int ms = 0; ms < 4; ++ms)
#pragma unroll
                for (int ns = 0; ns < NS; ++ns)
                    acc[ms][ns] = mfma16(af[ms], bf[ns], acc[ms][ns]);
        }
    }

    // epilogue (round-1 layout: col = l16, rows = quad*4+r)
#pragma unroll
    for (int ms = 0; ms < 4; ++ms) {
#pragma unroll
        for (int ns = 0; ns < NS; ++ns) {
            const int cg = n0 + wn * WN + ns * 16 + l16;
            const float bvc = VT ? 0.f : bias[cg];
#pragma unroll
            for (int r = 0; r < 4; ++r) {
                const int rg = m0 + wm * 64 + ms * 16 + quad * 4 + r;
                float v = acc[ms][ns][r] + (VT ? bias[rg] : bvc);
                if (RELU)   v = fmaxf(v, 0.0f);
                if (RES == 1)
                    v += res[(long long)rg * N + cg];
                if (VT) {
                    // rg = h*256+e (M=1024), cg = b*2048+t (N=16384) -> vt[(b*4+h)][e][t]
                    const long long oaddr =
                        (long long)((cg >> 11) * 4 + (rg >> 8)) * 524288 +
                        (long long)(rg & 255) * 2048 + (cg & 2047);
                    reinterpret_cast<unsigned short*>(out)[oaddr] = f2b(v);
                } else if (OUTBF) {
                    reinterpret_cast<unsigned short*>(out)[(long long)rg * N + cg] = f2b(v);
                } else {
                    reinterpret_cast<float*>(out)[(long long)rg * N + cg] = v;
                }
            }
        }
    }
}

template <bool RELU, int RES, bool OUTBF, int NS, bool VT, int BK>
__global__ __launch_bounds__(256) void gemm_kernel(
    const unsigned short* __restrict__ A, const unsigned short* __restrict__ BT,
    const float* __restrict__ bias, const float* __restrict__ res,
    void* __restrict__ out, int M, int N, int K)
{
    __shared__ unsigned short As[128 * (BK + 8)];
    __shared__ unsigned short Bs[(NS == 4 ? 128 : 64) * (BK + 8)];
    gemm_body<RELU, RES, OUTBF, NS, VT, BK>(As, Bs, A, BT, bias, res, out,
                                            M, N, K, blockIdx.x, blockIdx.y);
}

// merged QK-proj (blocks 0..2047) + V-proj (2048..3071); BK=64 (LDS 36.9KB -> 4/CU,
// matching the VGPR limit; K-iterations 8 -> 4)
__global__ __launch_bounds__(256) void qkv_kernel(
    const unsigned short* __restrict__ xn1, const unsigned short* __restrict__ wqkT,
    const unsigned short* __restrict__ wvT,
    const float* __restrict__ qkb, const float* __restrict__ vb,
    unsigned short* __restrict__ qk, unsigned short* __restrict__ vt)
{
    __shared__ unsigned short As[128 * 72];
    __shared__ unsigned short Bs[128 * 72];
    const int bid = blockIdx.x;
    if (bid < 2048) {
        gemm_body<false, 0, true, 4, false, 64>(As, Bs, xn1, wqkT, qkb, nullptr, qk,
                                                MM, 2048, 256, bid & 127, bid >> 7);
    } else {
        const int b2 = bid - 2048;
        gemm_body<false, 0, true, 4, true, 64>(As, Bs, wvT, xn1, vb, nullptr, vt,
                                               1024, MM, 256, b2 & 7, b2 >> 3);
    }
}

// ---------------- Flash attention (round-1 exact: 139.6-152 us band) ----------------
// K and V double-buffered in LDS via reg staging; in-register P (swapped QK^T + cvt_pk +
// permlane32_swap); split sc chains; __expf softmax; 1 barrier/iter.
// LDS: 2*(32*264 + 256*40)*2B = 74752 B -> 2 blocks/CU. ~90% of LDS-port roofline.
__global__ __launch_bounds__(256, 2) void attn_kernel(
    const unsigned short* __restrict__ QK, const unsigned short* __restrict__ Vt,
    unsigned short* __restrict__ Cat)
{
    __shared__ __align__(16) unsigned short Ks[2][32 * 264];   // [t][d], stride 264
    __shared__ __align__(16) unsigned short Vs[2][256 * 40];   // [e][t], stride 40
    const int tid  = threadIdx.x;
    const int wave = tid >> 6, lane = tid & 63;
    const int l32 = lane & 31, half = lane >> 5;
    const int by = blockIdx.x;              // b*4 + h
    const int h = by & 3, b = by >> 2;
    const int q0 = blockIdx.y * 128;
    const unsigned short* Qb = QK + (long long)b * SS * 2048 + h * 256;
    const unsigned short* Kb = Qb + 1024;
    const unsigned short* vbase = Vt + (long long)by * DD * SS;

    // Q fragments, 32 rows/wave: lane holds Q[q0+w*32+l32][kb*16 + half*8 + j]
    bf16x8 qf[16];
    {
        const unsigned short* qrow = Qb + (long long)(q0 + wave * 32 + l32) * 2048 + half * 8;
#pragma unroll
        for (int kb = 0; kb < 16; ++kb)
            qf[kb] = *reinterpret_cast<const bf16x8*>(qrow + kb * 16);
    }

    f32x16 o[8];
#pragma unroll
    for (int i = 0; i < 8; ++i)
#pragma unroll
        for (int r = 0; r < 16; ++r) o[i][r] = 0.f;
    float lsum = 0.f;   // per-lane partial row-sum for q = l32 (this half's t-subset)

    const int krow = tid >> 3;          // 0..31
    const int kcol = (tid & 7) * 8;     // 0..56 (shorts)
    const int ve   = tid >> 2;          // 0..63 (base V row)
    const int vtf  = (tid & 3) * 8;     // 0..24 (t offset, shorts)

    uint4 kreg[4], vreg[4];
    // prologue: stage tile 0 into buffer 0
#pragma unroll
    for (int c = 0; c < 4; ++c)
        kreg[c] = *reinterpret_cast<const uint4*>(&Kb[(long long)krow * 2048 + kcol + c * 64]);
#pragma unroll
    for (int c = 0; c < 4; ++c)
        vreg[c] = *reinterpret_cast<const uint4*>(&vbase[(long long)(ve + c * 64) * SS + vtf]);
#pragma unroll
    for (int c = 0; c < 4; ++c)
        *reinterpret_cast<uint4*>(&Ks[0][krow * 264 + kcol + c * 64]) = kreg[c];
#pragma unroll
    for (int c = 0; c < 4; ++c)
        *reinterpret_cast<uint4*>(&Vs[0][(ve + c * 64) * 40 + vtf]) = vreg[c];
    __syncthreads();

    for (int t = 0; t < 64; ++t) {
        const int cur = t & 1;
        // issue next-tile global loads early (latency hides under compute)
        if (t < 63) {
            const int t1 = (t + 1) * 32;
#pragma unroll
            for (int c = 0; c < 4; ++c)
                kreg[c] = *reinterpret_cast<const uint4*>(&Kb[(long long)(t1 + krow) * 2048 + kcol + c * 64]);
#pragma unroll
            for (int c = 0; c < 4; ++c)
                vreg[c] = *reinterpret_cast<const uint4*>(&vbase[(long long)(ve + c * 64) * SS + t1 + vtf]);
        }

        // swapped QK^T: sc = K_tile . Q^T -> lane holds S[q=l32][t-subset], split acc chain
        f32x16 sc0, sc1;
#pragma unroll
        for (int r = 0; r < 16; ++r) { sc0[r] = 0.f; sc1[r] = 0.f; }
        __builtin_amdgcn_s_setprio(1);
#pragma unroll
        for (int kb = 0; kb < 8; ++kb) {
            bf16x8 kf0 = *reinterpret_cast<const bf16x8*>(&Ks[cur][l32 * 264 + (2 * kb) * 16 + half * 8]);
            bf16x8 kf1 = *reinterpret_cast<const bf16x8*>(&Ks[cur][l32 * 264 + (2 * kb + 1) * 16 + half * 8]);
            sc0 = mfma32(kf0, qf[2 * kb], sc0);
            sc1 = mfma32(kf1, qf[2 * kb + 1], sc1);
        }
        __builtin_amdgcn_s_setprio(0);

        // softmax numerator: p = exp(s); accumulate row-sums per lane
        float p[16];
#pragma unroll
        for (int r = 0; r < 16; ++r) {
            p[r] = __expf(sc0[r] + sc1[r]);
            lsum += p[r];
        }

        // pack P -> PV A-fragments fully in-register (cvt_pk + permlane32_swap)
        unsigned pk[8];
#pragma unroll
        for (int i = 0; i < 8; ++i) pk[i] = cvtpk(p[2 * i], p[2 * i + 1]);
        union { bf16x8 v; unsigned u[4]; } A0, A1;   // A0: t=0..15, A1: t=16..31
        { auto rr = __builtin_amdgcn_permlane32_swap(pk[0], pk[2], false, false); A0.u[0] = rr[0]; A0.u[2] = rr[1]; }
        { auto rr = __builtin_amdgcn_permlane32_swap(pk[1], pk[3], false, false); A0.u[1] = rr[0]; A0.u[3] = rr[1]; }
        { auto rr = __builtin_amdgcn_permlane32_swap(pk[4], pk[6], false, false); A1.u[0] = rr[0]; A1.u[2] = rr[1]; }
        { auto rr = __builtin_amdgcn_permlane32_swap(pk[5], pk[7], false, false); A1.u[1] = rr[0]; A1.u[3] = rr[1]; }

        // PV: B = V^T tile from Vs; 8 e-tiles x 2 k-steps
        __builtin_amdgcn_s_setprio(1);
#pragma unroll
        for (int et = 0; et < 8; ++et) {
            bf16x8 vf0 = *reinterpret_cast<const bf16x8*>(&Vs[cur][(et * 32 + l32) * 40 + half * 8]);
            bf16x8 vf1 = *reinterpret_cast<const bf16x8*>(&Vs[cur][(et * 32 + l32) * 40 + 16 + half * 8]);
            o[et] = mfma32(A0.v, vf0, o[et]);
            o[et] = mfma32(A1.v, vf1, o[et]);
        }
        __builtin_amdgcn_s_setprio(0);

        // write next tile into the other buffer, then single barrier
        if (t < 63) {
            const int nxt = cur ^ 1;
#pragma unroll
            for (int c = 0; c < 4; ++c)
                *reinterpret_cast<uint4*>(&Ks[nxt][krow * 264 + kcol + c * 64]) = kreg[c];
#pragma unroll
            for (int c = 0; c < 4; ++c)
                *reinterpret_cast<uint4*>(&Vs[nxt][(ve + c * 64) * 40 + vtf]) = vreg[c];
            __syncthreads();
        }
    }

    // epilogue: full row-sum for q=l32 lives split across the two halves
    lsum += __shfl_xor(lsum, 32);
    const float inv = 1.0f / lsum;
    float invr[16];
#pragma unroll
    for (int r = 0; r < 16; ++r)
        invr[r] = __shfl(inv, (r & 3) + 8 * (r >> 2) + 4 * half);

    const int rowb = b * SS + q0 + wave * 32;
#pragma unroll
    for (int et = 0; et < 8; ++et) {
        const int cg = h * 256 + et * 32 + l32;
#pragma unroll
        for (int r = 0; r < 16; ++r) {
            const int row = (r & 3) + 8 * (r >> 2) + 4 * half;
            Cat[(long long)(rowb + row) * (HH * DD) + cg] = f2b(o[et][r] * invr[r]);
        }
    }
}

// ---------------- launch ----------------
extern "C" void kernel_launch(void* const* d_in, const int* in_sizes, int n_in,
                              void* d_out, int out_size, void* d_ws, size_t ws_size,
                              hipStream_t stream)
{
    const float* x   = (const float*)d_in[0];
    const float* Wq  = (const float*)d_in[1];
    const float* bq  = (const float*)d_in[2];
    const float* Wk  = (const float*)d_in[3];
    const float* bk  = (const float*)d_in[4];
    const float* Wv  = (const float*)d_in[5];
    const float* bv  = (const float*)d_in[6];
    const float* Wo  = (const float*)d_in[7];
    const float* bo  = (const float*)d_in[8];
    const float* g1  = (const float*)d_in[9];
    const float* be1 = (const float*)d_in[10];
    const float* g2  = (const float*)d_in[11];
    const float* be2 = (const float*)d_in[12];
    const float* W1  = (const float*)d_in[13];
    const float* bf1 = (const float*)d_in[14];
    const float* W2  = (const float*)d_in[15];
    const float* bf2 = (const float*)d_in[16];
    float* out = (float*)d_out;

    // ---- workspace layout ----
    char* ws = (char*)d_ws;
    unsigned short* xn1  = (unsigned short*)(ws + 0);           // [16384][256] bf16
    unsigned short* qk   = (unsigned short*)(ws + 8388608);     // [16384][2048] bf16 (Q|K by head)
    unsigned short* cat  = (unsigned short*)(ws + 75497472);    // [16384][1024] bf16
    unsigned short* vt   = (unsigned short*)(ws + 109051904);   // [32][256][2048] bf16
    unsigned short* wqkT = (unsigned short*)(ws + 142606336);   // [2048][256] bf16
    unsigned short* wvT  = (unsigned short*)(ws + 143654912);   // [1024][256] bf16
    unsigned short* woT  = (unsigned short*)(ws + 144179200);   // [256][1024] bf16
    unsigned short* w1T  = (unsigned short*)(ws + 144703488);   // [512][256] bf16
    unsigned short* w2T  = (unsigned short*)(ws + 144965632);   // [256][512] bf16
    float*          qkb  = (float*)(ws + 145227776);            // [2048] f32
    float*          vb   = (float*)(ws + 145235968);            // [1024] f32
    // aliases over dead regions:
    float*          xmid = (float*)(ws + 8388608);              // (qk dead after attn)
    unsigned short* xn2  = (unsigned short*)(ws + 25165824);
    unsigned short* mid  = (unsigned short*)(ws + 33554432);

    // fused prologue: all weight transposes + bias concat + LN1 in ONE dispatch
    prologue_kernel<<<dim3(4428), 256, 0, stream>>>(
        Wq, Wk, Wv, Wo, W1, W2, bq, bk, bv, x, g1, be1,
        wqkT, wvT, woT, w1T, w2T, qkb, vb, xn1);

    // merged Q|K projection + V^T projection (3072 blocks, one dispatch, BK=64)
    qkv_kernel<<<dim3(3072), 256, 0, stream>>>(xn1, wqkT, wvT, qkb, vb, qk, vt);

    // flash attention (32x32 MFMA, 128 q-rows/block, 512 blocks = 2/CU)
    attn_kernel<<<dim3(32, 16), 256, 0, stream>>>(qk, vt, cat);

    // Wo projection + residual(x) -> xmid (f32); BK=128 (8 iters), 512 blocks (2/CU, LDS->3)
    gemm_kernel<false, 1, false, 2, false, 128><<<dim3(128, 4), 256, 0, stream>>>(
        cat, woT, bo, x, xmid, MM, 256, 1024);

    // LN2
    ln_kernel<<<dim3(4096), 256, 0, stream>>>(xmid, g2, be2, xn2);

    // FFN1 + ReLU; BK=64 (4 iters), 1024 blocks (4/CU; BK=128 would cap LDS at 3 -> keep 64)
    gemm_kernel<true, 0, true, 2, false, 64><<<dim3(128, 8), 256, 0, stream>>>(
        xn2, w1T, bf1, nullptr, mid, MM, 512, 256);

    // FFN2 + residual(xmid) -> d_out (f32); BK=128 (4 iters), 512 blocks (2/CU, LDS->3)
    gemm_kernel<false, 1, false, 2, false, 128><<<dim3(128, 4), 256, 0, stream>>>(
        mid, w2T, bf2, xmid, out, MM, 256, 512);

    (void)in_sizes; (void)n_in; (void)out_size; (void)ws_size;
}